// Round 6
// baseline (449.289 us; speedup 1.0000x reference)
//
#include <hip/hip_runtime.h>
#include <hip/hip_bf16.h>
#include <hip/hip_cooperative_groups.h>
#include <cmath>

namespace cg = cooperative_groups;

#define BB 2
#define TT 64
#define CC 384
#define HH 768
#define GRID 512

// d_out flat offsets (fp32 elements): out, nW0, nb0, nW1, nb1
#define O_OUT 0
#define O_NW0 768
#define O_NB0 (768 + 589824)
#define O_NW1 (O_NB0 + 1536)
#define O_NB1 (O_NW1 + 589824)

struct Coefs { float ct[TT]; float dfac; };

typedef __attribute__((ext_vector_type(8))) short bf16x8;
typedef __attribute__((ext_vector_type(4))) float f32x4;

struct Args {
    const float *x, *Wq, *bq, *Wk, *bk, *Wv, *bv, *Wo, *bo, *iq, *sW0, *sb0, *sW1, *sb1;
    unsigned short *x_bf, *Wk_bf, *Wv_bf, *sW0_bf, *sW1_bf, *sW1T_bf;
    unsigned short *kb_bf, *h1_bf, *dp_bf, *dh1p_bf;
    float *vb, *dsil, *qb, *hret, *pred;
    float *out;
    Coefs cf;
};

__device__ __forceinline__ float bf2f(unsigned short u) {
    union { unsigned int i; float f; } x; x.i = ((unsigned int)u) << 16; return x.f;
}
__device__ __forceinline__ unsigned short f2bf(float f) {
    union { float f; unsigned int i; } u; u.f = f;
    unsigned int x = u.i;
    unsigned int r = (x + 0x7fffu + ((x >> 16) & 1u)) >> 16;  // RNE
    return (unsigned short)r;
}
__device__ __forceinline__ f32x4 mfma16(bf16x8 a, bf16x8 b, f32x4 c) {
    return __builtin_amdgcn_mfma_f32_16x16x32_bf16(a, b, c, 0, 0, 0);
}
__device__ __forceinline__ bf16x8 ldbf8(const unsigned short* p) {
    return *(const bf16x8*)p;
}

// single fused cooperative kernel; smem unioned across phases (24 KB)
__global__ void __launch_bounds__(256, 2) k_fused(Args A) {
    __shared__ float smem[6144];   // epi: a_t[64*32] + e_t[64*64]; gemv: vecs[<=768] + part@1024; tile: 32*33
    cg::grid_group grid = cg::this_grid();
    const int blk = blockIdx.x, j = threadIdx.x;
    const Coefs& cf = A.cf;

    // ================= phase 0: fp32 -> bf16 conversions =================
    {
        // flat: x(12288 f4) Wk(36864) Wv(36864) sW0(147456) = 233472 float4
        int tid = blk * 256 + j;                       // 131072 threads
        for (int g = tid; g < 233472; g += GRID * 256) {
            const float* src; unsigned short* dst; int off;
            if      (g < 12288) { src = A.x;   dst = A.x_bf;   off = g; }
            else if (g < 49152) { src = A.Wk;  dst = A.Wk_bf;  off = g - 12288; }
            else if (g < 86016) { src = A.Wv;  dst = A.Wv_bf;  off = g - 49152; }
            else                { src = A.sW0; dst = A.sW0_bf; off = g - 86016; }
            float4 v = ((const float4*)src)[off];
            ushort4 u;
            u.x = f2bf(v.x); u.y = f2bf(v.y); u.z = f2bf(v.z); u.w = f2bf(v.w);
            ((ushort4*)dst)[off] = u;
        }
        // sW1 -> sW1_bf (direct) + sW1T_bf (transposed), 576 32x32 tiles
        for (int u = blk; u < 576; u += GRID) {
            const int b = u / 288, rem = u % 288;
            const int c0 = (rem / 24) * 32, h0 = (rem % 24) * 32;
            const int row0 = j >> 5, col = j & 31;
            __syncthreads();
            #pragma unroll
            for (int r = 0; r < 4; ++r) {
                int row = row0 + r * 8;
                smem[row * 33 + col] = A.sW1[((size_t)(b * CC + c0 + row)) * HH + h0 + col];
            }
            __syncthreads();
            #pragma unroll
            for (int r = 0; r < 4; ++r) {
                int row = row0 + r * 8;
                A.sW1_bf [((size_t)(b * CC + c0 + row)) * HH + h0 + col] = f2bf(smem[row * 33 + col]);
                A.sW1T_bf[((size_t)(b * HH + h0 + row)) * CC + c0 + col] = f2bf(smem[col * 33 + row]);
            }
        }
    }
    grid.sync();

    // ================= phase 1: k|v MFMA + q GEMV =================
    if (blk < 24) {
        const int wid = j >> 6, L = j & 63;
        const int w = blk * 4 + wid;
        const int mp = w % 4, np = w / 4;
        const int lrow = L & 15, kq = (L >> 4) * 8;
        const unsigned short* A0 = A.x_bf + (size_t)(mp * 32 + lrow) * CC;
        const unsigned short* A1 = A0 + 16 * CC;
        const int n0 = (2 * np) * 16 + lrow, n1 = n0 + 16;
        const unsigned short* B0 = (n0 < CC) ? (A.Wk_bf + (size_t)n0 * CC) : (A.Wv_bf + (size_t)(n0 - CC) * CC);
        const unsigned short* B1 = (n1 < CC) ? (A.Wk_bf + (size_t)n1 * CC) : (A.Wv_bf + (size_t)(n1 - CC) * CC);
        f32x4 acc00 = {0,0,0,0}, acc01 = {0,0,0,0}, acc10 = {0,0,0,0}, acc11 = {0,0,0,0};
        for (int s = 0; s < CC / 32; ++s) {
            int k = s * 32 + kq;
            bf16x8 a0 = ldbf8(A0 + k), a1 = ldbf8(A1 + k);
            bf16x8 b0 = ldbf8(B0 + k), b1 = ldbf8(B1 + k);
            acc00 = mfma16(a0, b0, acc00); acc01 = mfma16(a0, b1, acc01);
            acc10 = mfma16(a1, b0, acc10); acc11 = mfma16(a1, b1, acc11);
        }
        const int quad = L >> 4;
        #pragma unroll
        for (int mi = 0; mi < 2; ++mi) {
            #pragma unroll
            for (int ni = 0; ni < 2; ++ni) {
                f32x4 acc = mi == 0 ? (ni == 0 ? acc00 : acc01) : (ni == 0 ? acc10 : acc11);
                int n = (2 * np + ni) * 16 + lrow;
                #pragma unroll
                for (int r = 0; r < 4; ++r) {
                    int m = mp * 32 + mi * 16 + quad * 4 + r;
                    float v = acc[r];
                    if (n < CC) A.kb_bf[(size_t)m * CC + n] = f2bf(v + A.bk[n]);
                    else        A.vb[(size_t)m * CC + (n - CC)] = v + A.bv[n - CC];
                }
            }
        }
    } else if (blk < 48) {
        // q = iq @ Wq^T + bq  (fp32 all the way)
        if (j < CC / 4) ((float4*)smem)[j] = ((const float4*)A.iq)[j];
        __syncthreads();
        const int nt = blk - 24;
        const int nl = j & 15, ks = j >> 4;
        const int n = nt * 16 + nl;
        const float4* wr = (const float4*)(A.Wq + (size_t)n * CC + ks * 24);
        float s = 0.f;
        #pragma unroll
        for (int i = 0; i < 6; ++i) {
            float4 a = wr[i];
            const float* v = smem + ks * 24 + i * 4;
            s += a.x * v[0] + a.y * v[1] + a.z * v[2] + a.w * v[3];
        }
        smem[1024 + ks * 17 + nl] = s;
        __syncthreads();
        if (j < 16) {
            float acc = A.bq[nt * 16 + j];
            #pragma unroll
            for (int kk = 0; kk < 16; ++kk) acc += smem[1024 + kk * 17 + j];
            A.qb[nt * 16 + j] = acc;
        }
    }
    grid.sync();

    // ================= phase 2: h1 = silu(kb @ sW0^T + sb0) + hret GEMV =================
    if (blk < 24) {
        const int b = blk / 12;
        const int wid = j >> 6, L = j & 63;
        const int w = (blk % 12) * 4 + wid;
        const int mp = w & 1, np = w >> 1;
        const int lrow = L & 15, kq = (L >> 4) * 8;
        const unsigned short* A0 = A.kb_bf + (size_t)(b * TT + mp * 32 + lrow) * CC;
        const unsigned short* A1 = A0 + 16 * CC;
        const int n0 = (2 * np) * 16 + lrow;
        const unsigned short* B0 = A.sW0_bf + (size_t)(b * HH + n0) * CC;
        const unsigned short* B1 = B0 + 16 * CC;
        f32x4 acc00 = {0,0,0,0}, acc01 = {0,0,0,0}, acc10 = {0,0,0,0}, acc11 = {0,0,0,0};
        for (int s = 0; s < CC / 32; ++s) {
            int k = s * 32 + kq;
            bf16x8 a0 = ldbf8(A0 + k), a1 = ldbf8(A1 + k);
            bf16x8 b0 = ldbf8(B0 + k), b1 = ldbf8(B1 + k);
            acc00 = mfma16(a0, b0, acc00); acc01 = mfma16(a0, b1, acc01);
            acc10 = mfma16(a1, b0, acc10); acc11 = mfma16(a1, b1, acc11);
        }
        const int quad = L >> 4;
        #pragma unroll
        for (int mi = 0; mi < 2; ++mi) {
            #pragma unroll
            for (int ni = 0; ni < 2; ++ni) {
                f32x4 acc = mi == 0 ? (ni == 0 ? acc00 : acc01) : (ni == 0 ? acc10 : acc11);
                int n = (2 * np + ni) * 16 + lrow;
                float bias = A.sb0[b * HH + n];
                #pragma unroll
                for (int r = 0; r < 4; ++r) {
                    int t = mp * 32 + mi * 16 + quad * 4 + r;
                    float pre = acc[r] + bias;
                    float sig = 1.f / (1.f + expf(-pre));
                    size_t idx = (size_t)(b * TT + t) * HH + n;
                    A.h1_bf[idx] = f2bf(pre * sig);
                    A.dsil[idx]  = sig * (1.f + pre * (1.f - sig));
                }
            }
        }
    } else if (blk < 120) {
        if (j < CC / 4) ((float4*)smem)[j] = ((const float4*)A.qb)[j];
        __syncthreads();
        const int rb = blk - 24;
        const int b = rb / 48, nt = rb % 48;
        const int nl = j & 15, ks = j >> 4;
        const int n = nt * 16 + nl;
        const float4* wr = (const float4*)(A.sW0 + (size_t)(b * HH + n) * CC + ks * 24);
        float s = 0.f;
        #pragma unroll
        for (int i = 0; i < 6; ++i) {
            float4 a = wr[i];
            const float* v = smem + ks * 24 + i * 4;
            s += a.x * v[0] + a.y * v[1] + a.z * v[2] + a.w * v[3];
        }
        smem[1024 + ks * 17 + nl] = s;
        __syncthreads();
        if (j < 16) {
            int n2 = nt * 16 + j;
            float pre = A.sb0[b * HH + n2];
            #pragma unroll
            for (int kk = 0; kk < 16; ++kk) pre += smem[1024 + kk * 17 + j];
            float sig = 1.f / (1.f + expf(-pre));
            A.hret[b * HH + n2] = pre * sig;
        }
    }
    grid.sync();

    // ================= phase 3: dp = (h1 @ sW1^T + sb1) - v + pred GEMV =================
    if (blk < 12) {
        const int b = blk / 6;
        const int wid = j >> 6, L = j & 63;
        const int w = (blk % 6) * 4 + wid;
        const int mp = w & 1, np = w >> 1;
        const int lrow = L & 15, kq = (L >> 4) * 8;
        const unsigned short* A0 = A.h1_bf + (size_t)(b * TT + mp * 32 + lrow) * HH;
        const unsigned short* A1 = A0 + 16 * HH;
        const int n0 = (2 * np) * 16 + lrow;
        const unsigned short* B0 = A.sW1_bf + (size_t)(b * CC + n0) * HH;
        const unsigned short* B1 = B0 + 16 * HH;
        f32x4 acc00 = {0,0,0,0}, acc01 = {0,0,0,0}, acc10 = {0,0,0,0}, acc11 = {0,0,0,0};
        for (int s = 0; s < HH / 32; ++s) {
            int k = s * 32 + kq;
            bf16x8 a0 = ldbf8(A0 + k), a1 = ldbf8(A1 + k);
            bf16x8 b0 = ldbf8(B0 + k), b1 = ldbf8(B1 + k);
            acc00 = mfma16(a0, b0, acc00); acc01 = mfma16(a0, b1, acc01);
            acc10 = mfma16(a1, b0, acc10); acc11 = mfma16(a1, b1, acc11);
        }
        const int quad = L >> 4;
        #pragma unroll
        for (int mi = 0; mi < 2; ++mi) {
            #pragma unroll
            for (int ni = 0; ni < 2; ++ni) {
                f32x4 acc = mi == 0 ? (ni == 0 ? acc00 : acc01) : (ni == 0 ? acc10 : acc11);
                int n = (2 * np + ni) * 16 + lrow;
                float bias = A.sb1[b * CC + n];
                #pragma unroll
                for (int r = 0; r < 4; ++r) {
                    int t = mp * 32 + mi * 16 + quad * 4 + r;
                    size_t idx = (size_t)(b * TT + t) * CC + n;
                    A.dp_bf[idx] = f2bf(acc[r] + bias - A.vb[idx]);
                }
            }
        }
    } else if (blk < 60) {
        const int rb = blk - 12;
        const int b = rb / 24, nt = rb % 24;
        if (j < HH / 4) ((float4*)smem)[j] = ((const float4*)(A.hret + b * HH))[j];
        __syncthreads();
        const int nl = j & 15, ks = j >> 4;
        const int n = nt * 16 + nl;
        const float4* wr = (const float4*)(A.sW1 + (size_t)(b * CC + n) * HH + ks * 48);
        float s = 0.f;
        #pragma unroll
        for (int i = 0; i < 12; ++i) {
            float4 a = wr[i];
            const float* v = smem + ks * 48 + i * 4;
            s += a.x * v[0] + a.y * v[1] + a.z * v[2] + a.w * v[3];
        }
        smem[1024 + ks * 17 + nl] = s;
        __syncthreads();
        if (j < 16) {
            int n2 = nt * 16 + j;
            float acc = A.sb1[b * CC + n2];
            #pragma unroll
            for (int kk = 0; kk < 16; ++kk) acc += smem[1024 + kk * 17 + j];
            A.pred[b * CC + n2] = acc;
        }
    }
    grid.sync();

    // ================= phase 4: dh1p = (dp @ sW1T^T) * dsil =================
    if (blk < 24) {
        const int b = blk / 12;
        const int wid = j >> 6, L = j & 63;
        const int w = (blk % 12) * 4 + wid;
        const int mp = w & 1, np = w >> 1;
        const int lrow = L & 15, kq = (L >> 4) * 8;
        const unsigned short* A0 = A.dp_bf + (size_t)(b * TT + mp * 32 + lrow) * CC;
        const unsigned short* A1 = A0 + 16 * CC;
        const int n0 = (2 * np) * 16 + lrow;
        const unsigned short* B0 = A.sW1T_bf + (size_t)(b * HH + n0) * CC;
        const unsigned short* B1 = B0 + 16 * CC;
        f32x4 acc00 = {0,0,0,0}, acc01 = {0,0,0,0}, acc10 = {0,0,0,0}, acc11 = {0,0,0,0};
        for (int s = 0; s < CC / 32; ++s) {
            int k = s * 32 + kq;
            bf16x8 a0 = ldbf8(A0 + k), a1 = ldbf8(A1 + k);
            bf16x8 b0 = ldbf8(B0 + k), b1 = ldbf8(B1 + k);
            acc00 = mfma16(a0, b0, acc00); acc01 = mfma16(a0, b1, acc01);
            acc10 = mfma16(a1, b0, acc10); acc11 = mfma16(a1, b1, acc11);
        }
        const int quad = L >> 4;
        #pragma unroll
        for (int mi = 0; mi < 2; ++mi) {
            #pragma unroll
            for (int ni = 0; ni < 2; ++ni) {
                f32x4 acc = mi == 0 ? (ni == 0 ? acc00 : acc01) : (ni == 0 ? acc10 : acc11);
                int n = (2 * np + ni) * 16 + lrow;
                #pragma unroll
                for (int r = 0; r < 4; ++r) {
                    int t = mp * 32 + mi * 16 + quad * 4 + r;
                    size_t idx = (size_t)(b * TT + t) * HH + n;
                    A.dh1p_bf[idx] = f2bf(acc[r] * A.dsil[idx]);
                }
            }
        }
    }
    grid.sync();

    // ================= phase 5: epilogue, 626 units over GRID blocks =================
    for (int u = blk; u < 626; u += GRID) {
        __syncthreads();
        if (u < 288) {                       // nW1 tile 32c x 64h
            float* a_t = smem;               // [64][32]
            float* e_t = smem + 2048;        // [64][64]
            const int b = u / 144, rem = u % 144;
            const int c0 = (rem / 12) * 32, h0 = (rem % 12) * 64;
            for (int i = j; i < TT * 32; i += 256) {
                int t = i >> 5, c = i & 31;
                a_t[t * 32 + c] = cf.ct[t] * bf2f(A.dp_bf[((size_t)(b * TT + t)) * CC + c0 + c]);
            }
            for (int i = j; i < TT * 64; i += 256) {
                int t = i >> 6, h = i & 63;
                e_t[t * 64 + h] = bf2f(A.h1_bf[((size_t)(b * TT + t)) * HH + h0 + h]);
            }
            __syncthreads();
            const int ci = j & 31, hb = (j >> 5) * 8;
            float acc[8] = {0, 0, 0, 0, 0, 0, 0, 0};
            for (int t = 0; t < TT; ++t) {
                float av = a_t[t * 32 + ci];
                #pragma unroll
                for (int m = 0; m < 8; ++m) acc[m] += av * e_t[t * 64 + hb + m];
            }
            const size_t idx = ((size_t)b * CC + c0 + ci) * HH + h0 + hb;
            const float4* w4 = (const float4*)(A.sW1 + idx);
            float4 wa = w4[0], wb = w4[1];
            float4 o0, o1;
            o0.x = cf.dfac * wa.x - acc[0]; o0.y = cf.dfac * wa.y - acc[1];
            o0.z = cf.dfac * wa.z - acc[2]; o0.w = cf.dfac * wa.w - acc[3];
            o1.x = cf.dfac * wb.x - acc[4]; o1.y = cf.dfac * wb.y - acc[5];
            o1.z = cf.dfac * wb.z - acc[6]; o1.w = cf.dfac * wb.w - acc[7];
            *(float4*)(A.out + O_NW1 + idx) = o0;
            *(float4*)(A.out + O_NW1 + idx + 4) = o1;
        } else if (u < 576) {                // nW0 tile 32h x 64c
            float* a_t = smem;
            float* e_t = smem + 2048;
            const int u2 = u - 288;
            const int b = u2 / 144, rem = u2 % 144;
            const int h0 = (rem / 6) * 32, c0 = (rem % 6) * 64;
            for (int i = j; i < TT * 32; i += 256) {
                int t = i >> 5, h = i & 31;
                a_t[t * 32 + h] = cf.ct[t] * bf2f(A.dh1p_bf[((size_t)(b * TT + t)) * HH + h0 + h]);
            }
            for (int i = j; i < TT * 64; i += 256) {
                int t = i >> 6, c = i & 63;
                e_t[t * 64 + c] = bf2f(A.kb_bf[((size_t)(b * TT + t)) * CC + c0 + c]);
            }
            __syncthreads();
            const int hi = j & 31, cb = (j >> 5) * 8;
            float acc[8] = {0, 0, 0, 0, 0, 0, 0, 0};
            for (int t = 0; t < TT; ++t) {
                float av = a_t[t * 32 + hi];
                #pragma unroll
                for (int m = 0; m < 8; ++m) acc[m] += av * e_t[t * 64 + cb + m];
            }
            const size_t idx = ((size_t)b * HH + h0 + hi) * CC + c0 + cb;
            const float4* w4 = (const float4*)(A.sW0 + idx);
            float4 wa = w4[0], wb = w4[1];
            float4 o0, o1;
            o0.x = cf.dfac * wa.x - acc[0]; o0.y = cf.dfac * wa.y - acc[1];
            o0.z = cf.dfac * wa.z - acc[2]; o0.w = cf.dfac * wa.w - acc[3];
            o1.x = cf.dfac * wb.x - acc[4]; o1.y = cf.dfac * wb.y - acc[5];
            o1.z = cf.dfac * wb.z - acc[6]; o1.w = cf.dfac * wb.w - acc[7];
            *(float4*)(A.out + O_NW0 + idx) = o0;
            *(float4*)(A.out + O_NW0 + idx + 4) = o1;
        } else if (u < 624) {                // out = pred@Wo^T + bo (fp32)
            const int rb = u - 576;
            const int b = rb / 24, nt = rb % 24;
            if (j < CC / 4) ((float4*)smem)[j] = ((const float4*)(A.pred + b * CC))[j];
            __syncthreads();
            const int nl = j & 15, ks = j >> 4;
            const int n = nt * 16 + nl;
            const float4* wr = (const float4*)(A.Wo + (size_t)n * CC + ks * 24);
            float s = 0.f;
            #pragma unroll
            for (int i = 0; i < 6; ++i) {
                float4 a = wr[i];
                const float* v = smem + ks * 24 + i * 4;
                s += a.x * v[0] + a.y * v[1] + a.z * v[2] + a.w * v[3];
            }
            smem[1024 + ks * 17 + nl] = s;
            __syncthreads();
            if (j < 16) {
                int n2 = nt * 16 + j;
                float acc = A.bo[n2];
                #pragma unroll
                for (int kk = 0; kk < 16; ++kk) acc += smem[1024 + kk * 17 + j];
                A.out[O_OUT + b * CC + n2] = acc;
            }
        } else {                             // nb1, nb0
            const int b = u - 624;
            for (int c = j; c < CC; c += 256) {
                float acc = 0.f;
                for (int t = 0; t < TT; ++t)
                    acc += cf.ct[t] * bf2f(A.dp_bf[((size_t)(b * TT + t)) * CC + c]);
                A.out[O_NB1 + b * CC + c] = cf.dfac * A.sb1[b * CC + c] - acc;
            }
            for (int h = j; h < HH; h += 256) {
                float acc = 0.f;
                for (int t = 0; t < TT; ++t)
                    acc += cf.ct[t] * bf2f(A.dh1p_bf[((size_t)(b * TT + t)) * HH + h]);
                A.out[O_NB0 + b * HH + h] = cf.dfac * A.sb0[b * HH + h] - acc;
            }
        }
    }
}

extern "C" void kernel_launch(void* const* d_in, const int* in_sizes, int n_in,
                              void* d_out, int out_size, void* d_ws, size_t ws_size,
                              hipStream_t stream) {
    Args A;
    A.x   = (const float*)d_in[0];
    A.Wq  = (const float*)d_in[1];
    A.bq  = (const float*)d_in[2];
    A.Wk  = (const float*)d_in[3];
    A.bk  = (const float*)d_in[4];
    A.Wv  = (const float*)d_in[5];
    A.bv  = (const float*)d_in[6];
    A.Wo  = (const float*)d_in[7];
    A.bo  = (const float*)d_in[8];
    A.iq  = (const float*)d_in[9];
    A.sW0 = (const float*)d_in[10];
    A.sb0 = (const float*)d_in[11];
    A.sW1 = (const float*)d_in[12];
    A.sb1 = (const float*)d_in[13];
    A.out = (float*)d_out;

    float* fw = (float*)d_ws;
    A.qb   = fw;                 // 384
    A.hret = A.qb + 384;         // 1536
    A.pred = A.hret + 1536;      // 768
    A.vb   = A.pred + 768;       // 49152
    A.dsil = A.vb + 49152;       // 98304
    unsigned short* us = (unsigned short*)(A.dsil + 98304);
    A.x_bf    = us;               // 49152
    A.kb_bf   = A.x_bf + 49152;   // 49152
    A.h1_bf   = A.kb_bf + 49152;  // 98304
    A.dp_bf   = A.h1_bf + 98304;  // 49152
    A.dh1p_bf = A.dp_bf + 49152;  // 98304
    A.Wk_bf   = A.dh1p_bf + 98304; // 147456
    A.Wv_bf   = A.Wk_bf + 147456;  // 147456
    A.sW0_bf  = A.Wv_bf + 147456;  // 589824
    A.sW1_bf  = A.sW0_bf + 589824; // 589824
    A.sW1T_bf = A.sW1_bf + 589824; // 589824   (~4.5 MB total)

    // Closed-form scan coefficients (exact: the clipped seed gate cancels).
    const double mom = 0.9, decay = 1.0 - 0.001, lr = 0.01;
    for (int s = 0; s < TT; ++s) {
        double sum = 0.0;
        for (int t = s; t < TT; ++t) sum += pow(decay, (double)(TT - 1 - t)) * pow(mom, (double)(t - s));
        A.cf.ct[s] = (float)(lr * (1.0 - mom) * sum);
    }
    A.cf.dfac = (float)pow(decay, (double)TT);

    void* kargs[] = { (void*)&A };
    hipLaunchCooperativeKernel((const void*)k_fused, dim3(GRID), dim3(256), kargs, 0, stream);
}

// Round 7
// 145.757 us; speedup vs baseline: 3.0824x; 3.0824x over previous
//
#include <hip/hip_runtime.h>
#include <hip/hip_bf16.h>
#include <cmath>

#define BB 2
#define TT 64
#define CC 384
#define HH 768

// d_out flat offsets (fp32 elements): out, nW0, nb0, nW1, nb1
#define O_OUT 0
#define O_NW0 768
#define O_NB0 (768 + 589824)
#define O_NW1 (O_NB0 + 1536)
#define O_NB1 (O_NW1 + 589824)

struct Coefs { float ct[TT]; float dfac; };

typedef __attribute__((ext_vector_type(8))) short bf16x8;
typedef __attribute__((ext_vector_type(4))) float f32x4;

__device__ __forceinline__ float bf2f(unsigned short u) {
    union { unsigned int i; float f; } x; x.i = ((unsigned int)u) << 16; return x.f;
}
__device__ __forceinline__ unsigned short f2bf(float f) {
    union { float f; unsigned int i; } u; u.f = f;
    unsigned int x = u.i;
    unsigned int r = (x + 0x7fffu + ((x >> 16) & 1u)) >> 16;  // RNE
    return (unsigned short)r;
}
__device__ __forceinline__ f32x4 mfma16(bf16x8 a, bf16x8 b, f32x4 c) {
    return __builtin_amdgcn_mfma_f32_16x16x32_bf16(a, b, c, 0, 0, 0);
}
__device__ __forceinline__ bf16x8 ldbf8(const unsigned short* p) {
    return *(const bf16x8*)p;
}
// load 8 consecutive fp32, convert to bf16x8 in-register
__device__ __forceinline__ bf16x8 ldcvt8(const float* p) {
    float4 a = *(const float4*)p, b = *(const float4*)(p + 4);
    bf16x8 r;
    r[0] = (short)f2bf(a.x); r[1] = (short)f2bf(a.y); r[2] = (short)f2bf(a.z); r[3] = (short)f2bf(a.w);
    r[4] = (short)f2bf(b.x); r[5] = (short)f2bf(b.y); r[6] = (short)f2bf(b.z); r[7] = (short)f2bf(b.w);
    return r;
}
// load 8 strided fp32 (stride in elements), convert to bf16x8
__device__ __forceinline__ bf16x8 ldcvt8s(const float* p, int stride) {
    bf16x8 r;
    #pragma unroll
    for (int i = 0; i < 8; ++i) r[i] = (short)f2bf(p[(size_t)i * stride]);
    return r;
}

// ---------------- K1: k|v MFMA (in-reg cvt of x,Wk,Wv) + q GEMV ----------------
// blocks [0,24): MFMA, wave w=blk*4+wid in [0,96): mp=w%4 (M=128), np=w/4 (N=768: Wk|Wv)
// blocks [24,48): q GEMV (fp32)
__global__ void k_qkv(const float* __restrict__ x,
                      const float* __restrict__ Wk, const float* __restrict__ bk,
                      const float* __restrict__ Wv, const float* __restrict__ bv,
                      const float* __restrict__ Wq, const float* __restrict__ bq,
                      const float* __restrict__ iq,
                      unsigned short* __restrict__ kb_bf, float* __restrict__ vb,
                      float* __restrict__ qb) {
    __shared__ float smem[1024 + 16 * 17];
    const int blk = blockIdx.x, j = threadIdx.x;
    if (blk < 24) {
        const int wid = j >> 6, L = j & 63;
        const int w = blk * 4 + wid;
        const int mp = w % 4, np = w / 4;
        const int lrow = L & 15, kq = (L >> 4) * 8;
        const float* A0 = x + (size_t)(mp * 32 + lrow) * CC;
        const float* A1 = A0 + 16 * CC;
        const int n0 = (2 * np) * 16 + lrow, n1 = n0 + 16;
        const float* B0 = (n0 < CC) ? (Wk + (size_t)n0 * CC) : (Wv + (size_t)(n0 - CC) * CC);
        const float* B1 = (n1 < CC) ? (Wk + (size_t)n1 * CC) : (Wv + (size_t)(n1 - CC) * CC);
        f32x4 acc00 = {0,0,0,0}, acc01 = {0,0,0,0}, acc10 = {0,0,0,0}, acc11 = {0,0,0,0};
        #pragma unroll 2
        for (int s = 0; s < CC / 32; ++s) {
            int k = s * 32 + kq;
            bf16x8 a0 = ldcvt8(A0 + k), a1 = ldcvt8(A1 + k);
            bf16x8 b0 = ldcvt8(B0 + k), b1 = ldcvt8(B1 + k);
            acc00 = mfma16(a0, b0, acc00); acc01 = mfma16(a0, b1, acc01);
            acc10 = mfma16(a1, b0, acc10); acc11 = mfma16(a1, b1, acc11);
        }
        const int quad = L >> 4;
        #pragma unroll
        for (int mi = 0; mi < 2; ++mi) {
            #pragma unroll
            for (int ni = 0; ni < 2; ++ni) {
                f32x4 acc = mi == 0 ? (ni == 0 ? acc00 : acc01) : (ni == 0 ? acc10 : acc11);
                int n = (2 * np + ni) * 16 + lrow;
                #pragma unroll
                for (int r = 0; r < 4; ++r) {
                    int m = mp * 32 + mi * 16 + quad * 4 + r;
                    float v = acc[r];
                    if (n < CC) kb_bf[(size_t)m * CC + n] = f2bf(v + bk[n]);
                    else        vb[(size_t)m * CC + (n - CC)] = v + bv[n - CC];
                }
            }
        }
    } else {
        if (j < CC / 4) ((float4*)smem)[j] = ((const float4*)iq)[j];
        __syncthreads();
        const int nt = blk - 24;
        const int nl = j & 15, ks = j >> 4;
        const int n = nt * 16 + nl;
        const float4* wr = (const float4*)(Wq + (size_t)n * CC + ks * 24);
        float s = 0.f;
        #pragma unroll
        for (int i = 0; i < 6; ++i) {
            float4 a = wr[i];
            const float* v = smem + ks * 24 + i * 4;
            s += a.x * v[0] + a.y * v[1] + a.z * v[2] + a.w * v[3];
        }
        smem[1024 + ks * 17 + nl] = s;
        __syncthreads();
        if (j < 16) {
            float acc = bq[nt * 16 + j];
            #pragma unroll
            for (int kk = 0; kk < 16; ++kk) acc += smem[1024 + kk * 17 + j];
            qb[nt * 16 + j] = acc;
        }
    }
}

// ---------------- K2: h1 = silu(kb @ sW0^T + sb0) (in-reg cvt sW0) + hret GEMV ----------------
// blocks [0,24): MFMA per b (12 each): w=(blk%12)*4+wid in [0,48): mp=w&1, np=w>>1
// blocks [24,120): hret GEMV
__global__ void k_h1(const unsigned short* __restrict__ kb_bf, const float* __restrict__ qb,
                     const float* __restrict__ sW0, const float* __restrict__ sb0,
                     unsigned short* __restrict__ h1_bf, float* __restrict__ dsil,
                     float* __restrict__ hret) {
    __shared__ float smem[1024 + 16 * 17];
    const int blk = blockIdx.x, j = threadIdx.x;
    if (blk < 24) {
        const int b = blk / 12;
        const int wid = j >> 6, L = j & 63;
        const int w = (blk % 12) * 4 + wid;
        const int mp = w & 1, np = w >> 1;
        const int lrow = L & 15, kq = (L >> 4) * 8;
        const unsigned short* A0 = kb_bf + (size_t)(b * TT + mp * 32 + lrow) * CC;
        const unsigned short* A1 = A0 + 16 * CC;
        const int n0 = (2 * np) * 16 + lrow;
        const float* B0 = sW0 + (size_t)(b * HH + n0) * CC;
        const float* B1 = B0 + 16 * CC;
        f32x4 acc00 = {0,0,0,0}, acc01 = {0,0,0,0}, acc10 = {0,0,0,0}, acc11 = {0,0,0,0};
        #pragma unroll 2
        for (int s = 0; s < CC / 32; ++s) {
            int k = s * 32 + kq;
            bf16x8 a0 = ldbf8(A0 + k), a1 = ldbf8(A1 + k);
            bf16x8 b0 = ldcvt8(B0 + k), b1 = ldcvt8(B1 + k);
            acc00 = mfma16(a0, b0, acc00); acc01 = mfma16(a0, b1, acc01);
            acc10 = mfma16(a1, b0, acc10); acc11 = mfma16(a1, b1, acc11);
        }
        const int quad = L >> 4;
        #pragma unroll
        for (int mi = 0; mi < 2; ++mi) {
            #pragma unroll
            for (int ni = 0; ni < 2; ++ni) {
                f32x4 acc = mi == 0 ? (ni == 0 ? acc00 : acc01) : (ni == 0 ? acc10 : acc11);
                int n = (2 * np + ni) * 16 + lrow;
                float bias = sb0[b * HH + n];
                #pragma unroll
                for (int r = 0; r < 4; ++r) {
                    int t = mp * 32 + mi * 16 + quad * 4 + r;
                    float pre = acc[r] + bias;
                    float sig = 1.f / (1.f + expf(-pre));
                    size_t idx = (size_t)(b * TT + t) * HH + n;
                    h1_bf[idx] = f2bf(pre * sig);
                    dsil[idx]  = sig * (1.f + pre * (1.f - sig));
                }
            }
        }
    } else {
        if (j < CC / 4) ((float4*)smem)[j] = ((const float4*)qb)[j];
        __syncthreads();
        const int rb = blk - 24;
        const int b = rb / 48, nt = rb % 48;
        const int nl = j & 15, ks = j >> 4;
        const int n = nt * 16 + nl;
        const float4* wr = (const float4*)(sW0 + (size_t)(b * HH + n) * CC + ks * 24);
        float s = 0.f;
        #pragma unroll
        for (int i = 0; i < 6; ++i) {
            float4 a = wr[i];
            const float* v = smem + ks * 24 + i * 4;
            s += a.x * v[0] + a.y * v[1] + a.z * v[2] + a.w * v[3];
        }
        smem[1024 + ks * 17 + nl] = s;
        __syncthreads();
        if (j < 16) {
            int n2 = nt * 16 + j;
            float pre = sb0[b * HH + n2];
            #pragma unroll
            for (int kk = 0; kk < 16; ++kk) pre += smem[1024 + kk * 17 + j];
            float sig = 1.f / (1.f + expf(-pre));
            hret[b * HH + n2] = pre * sig;
        }
    }
}

// ---------------- K3: dp = (h1 @ sW1^T + sb1) - v (in-reg cvt sW1) + pred GEMV ----------------
// blocks [0,12): MFMA per b (6 each): w=(blk%6)*4+wid in [0,24): mp=w&1, np=w>>1
// blocks [12,60): pred GEMV (K=768)
__global__ void k_p(const unsigned short* __restrict__ h1_bf, const float* __restrict__ hret,
                    const float* __restrict__ vb,
                    const float* __restrict__ sW1, const float* __restrict__ sb1,
                    unsigned short* __restrict__ dp_bf, float* __restrict__ pred) {
    __shared__ float smem[1024 + 16 * 17];
    const int blk = blockIdx.x, j = threadIdx.x;
    if (blk < 12) {
        const int b = blk / 6;
        const int wid = j >> 6, L = j & 63;
        const int w = (blk % 6) * 4 + wid;
        const int mp = w & 1, np = w >> 1;
        const int lrow = L & 15, kq = (L >> 4) * 8;
        const unsigned short* A0 = h1_bf + (size_t)(b * TT + mp * 32 + lrow) * HH;
        const unsigned short* A1 = A0 + 16 * HH;
        const int n0 = (2 * np) * 16 + lrow;
        const float* B0 = sW1 + (size_t)(b * CC + n0) * HH;
        const float* B1 = B0 + 16 * HH;
        f32x4 acc00 = {0,0,0,0}, acc01 = {0,0,0,0}, acc10 = {0,0,0,0}, acc11 = {0,0,0,0};
        #pragma unroll 2
        for (int s = 0; s < HH / 32; ++s) {
            int k = s * 32 + kq;
            bf16x8 a0 = ldbf8(A0 + k), a1 = ldbf8(A1 + k);
            bf16x8 b0 = ldcvt8(B0 + k), b1 = ldcvt8(B1 + k);
            acc00 = mfma16(a0, b0, acc00); acc01 = mfma16(a0, b1, acc01);
            acc10 = mfma16(a1, b0, acc10); acc11 = mfma16(a1, b1, acc11);
        }
        const int quad = L >> 4;
        #pragma unroll
        for (int mi = 0; mi < 2; ++mi) {
            #pragma unroll
            for (int ni = 0; ni < 2; ++ni) {
                f32x4 acc = mi == 0 ? (ni == 0 ? acc00 : acc01) : (ni == 0 ? acc10 : acc11);
                int n = (2 * np + ni) * 16 + lrow;
                float bias = sb1[b * CC + n];
                #pragma unroll
                for (int r = 0; r < 4; ++r) {
                    int t = mp * 32 + mi * 16 + quad * 4 + r;
                    size_t idx = (size_t)(b * TT + t) * CC + n;
                    dp_bf[idx] = f2bf(acc[r] + bias - vb[idx]);
                }
            }
        }
    } else {
        const int rb = blk - 12;
        const int b = rb / 24, nt = rb % 24;
        if (j < HH / 4) ((float4*)smem)[j] = ((const float4*)(hret + b * HH))[j];
        __syncthreads();
        const int nl = j & 15, ks = j >> 4;
        const int n = nt * 16 + nl;
        const float4* wr = (const float4*)(sW1 + (size_t)(b * CC + n) * HH + ks * 48);
        float s = 0.f;
        #pragma unroll
        for (int i = 0; i < 12; ++i) {
            float4 a = wr[i];
            const float* v = smem + ks * 48 + i * 4;
            s += a.x * v[0] + a.y * v[1] + a.z * v[2] + a.w * v[3];
        }
        smem[1024 + ks * 17 + nl] = s;
        __syncthreads();
        if (j < 16) {
            int n2 = nt * 16 + j;
            float acc = sb1[b * CC + n2];
            #pragma unroll
            for (int kk = 0; kk < 16; ++kk) acc += smem[1024 + kk * 17 + j];
            pred[b * CC + n2] = acc;
        }
    }
}

// ---------------- K4: dh1p MFMA + nW1 tiles (+nb1) + out GEMV ----------------
// blocks [0,24):    dh1p = (dp @ sW1cols) * dsil   (B via strided fp32 gather)
// blocks [24,312):  nW1[b,c,h] = dfac*sW1 - sum_t (ct*dp)[t,c]*h1[t,h]; h0==0 blocks also nb1
// blocks [312,360): out = pred@Wo^T + bo
__global__ void k_epi1(const unsigned short* __restrict__ dp_bf,
                       const unsigned short* __restrict__ h1_bf,
                       const float* __restrict__ dsil,
                       const float* __restrict__ sW1, const float* __restrict__ sb1,
                       const float* __restrict__ pred,
                       const float* __restrict__ Wo, const float* __restrict__ bo,
                       unsigned short* __restrict__ dh1p_bf,
                       float* __restrict__ out, Coefs cf) {
    __shared__ float smem[6144];
    const int blk = blockIdx.x, j = threadIdx.x;
    if (blk < 24) {                       // dh1p MFMA
        const int b = blk / 12;
        const int wid = j >> 6, L = j & 63;
        const int w = (blk % 12) * 4 + wid;
        const int mp = w & 1, np = w >> 1;
        const int lrow = L & 15, kq = (L >> 4) * 8;
        const unsigned short* A0 = dp_bf + (size_t)(b * TT + mp * 32 + lrow) * CC;
        const unsigned short* A1 = A0 + 16 * CC;
        const int n0 = (2 * np) * 16 + lrow, n1 = n0 + 16;
        const float* Bb = sW1 + (size_t)b * CC * HH;
        f32x4 acc00 = {0,0,0,0}, acc01 = {0,0,0,0}, acc10 = {0,0,0,0}, acc11 = {0,0,0,0};
        for (int s = 0; s < CC / 32; ++s) {
            int k = s * 32 + kq;
            bf16x8 a0 = ldbf8(A0 + k), a1 = ldbf8(A1 + k);
            bf16x8 b0 = ldcvt8s(Bb + (size_t)k * HH + n0, HH);
            bf16x8 b1 = ldcvt8s(Bb + (size_t)k * HH + n1, HH);
            acc00 = mfma16(a0, b0, acc00); acc01 = mfma16(a0, b1, acc01);
            acc10 = mfma16(a1, b0, acc10); acc11 = mfma16(a1, b1, acc11);
        }
        const int quad = L >> 4;
        #pragma unroll
        for (int mi = 0; mi < 2; ++mi) {
            #pragma unroll
            for (int ni = 0; ni < 2; ++ni) {
                f32x4 acc = mi == 0 ? (ni == 0 ? acc00 : acc01) : (ni == 0 ? acc10 : acc11);
                int n = (2 * np + ni) * 16 + lrow;
                #pragma unroll
                for (int r = 0; r < 4; ++r) {
                    int t = mp * 32 + mi * 16 + quad * 4 + r;
                    size_t idx = (size_t)(b * TT + t) * HH + n;
                    dh1p_bf[idx] = f2bf(acc[r] * dsil[idx]);
                }
            }
        }
    } else if (blk < 312) {               // nW1 tile 32c x 64h
        float* a_t = smem;                // [64][32]
        float* e_t = smem + 2048;         // [64][64]
        const int u = blk - 24;
        const int b = u / 144, rem = u % 144;
        const int c0 = (rem / 12) * 32, h0 = (rem % 12) * 64;
        for (int i = j; i < TT * 32; i += 256) {
            int t = i >> 5, c = i & 31;
            a_t[t * 32 + c] = cf.ct[t] * bf2f(dp_bf[((size_t)(b * TT + t)) * CC + c0 + c]);
        }
        for (int i = j; i < TT * 64; i += 256) {
            int t = i >> 6, h = i & 63;
            e_t[t * 64 + h] = bf2f(h1_bf[((size_t)(b * TT + t)) * HH + h0 + h]);
        }
        __syncthreads();
        const int ci = j & 31, hb = (j >> 5) * 8;
        float acc[8] = {0, 0, 0, 0, 0, 0, 0, 0};
        for (int t = 0; t < TT; ++t) {
            float av = a_t[t * 32 + ci];
            #pragma unroll
            for (int m = 0; m < 8; ++m) acc[m] += av * e_t[t * 64 + hb + m];
        }
        const size_t idx = ((size_t)b * CC + c0 + ci) * HH + h0 + hb;
        const float4* w4 = (const float4*)(sW1 + idx);
        float4 wa = w4[0], wb = w4[1];
        float4 o0, o1;
        o0.x = cf.dfac * wa.x - acc[0]; o0.y = cf.dfac * wa.y - acc[1];
        o0.z = cf.dfac * wa.z - acc[2]; o0.w = cf.dfac * wa.w - acc[3];
        o1.x = cf.dfac * wb.x - acc[4]; o1.y = cf.dfac * wb.y - acc[5];
        o1.z = cf.dfac * wb.z - acc[6]; o1.w = cf.dfac * wb.w - acc[7];
        *(float4*)(out + O_NW1 + idx) = o0;
        *(float4*)(out + O_NW1 + idx + 4) = o1;
        if (h0 == 0 && j < 32) {          // nb1 for this c-range
            float s = 0.f;
            for (int t = 0; t < TT; ++t) s += a_t[t * 32 + j];
            out[O_NB1 + b * CC + c0 + j] = cf.dfac * sb1[b * CC + c0 + j] - s;
        }
    } else {                              // out = pred@Wo^T + bo
        const int rb = blk - 312;
        const int b = rb / 24, nt = rb % 24;
        if (j < CC / 4) ((float4*)smem)[j] = ((const float4*)(pred + b * CC))[j];
        __syncthreads();
        const int nl = j & 15, ks = j >> 4;
        const int n = nt * 16 + nl;
        const float4* wr = (const float4*)(Wo + (size_t)n * CC + ks * 24);
        float s = 0.f;
        #pragma unroll
        for (int i = 0; i < 6; ++i) {
            float4 a = wr[i];
            const float* v = smem + ks * 24 + i * 4;
            s += a.x * v[0] + a.y * v[1] + a.z * v[2] + a.w * v[3];
        }
        smem[1024 + ks * 17 + nl] = s;
        __syncthreads();
        if (j < 16) {
            int n2 = nt * 16 + j;
            float acc = bo[n2];
            #pragma unroll
            for (int kk = 0; kk < 16; ++kk) acc += smem[1024 + kk * 17 + j];
            out[O_OUT + b * CC + n2] = acc;
        }
    }
}

// ---------------- K5: nW0 tiles (+nb0) ----------------
// blocks [0,288): nW0[b,h,c] = dfac*sW0 - sum_t (ct*dh1p)[t,h]*k[t,c]; c0==0 blocks also nb0
__global__ void k_epi2(const unsigned short* __restrict__ dh1p_bf,
                       const unsigned short* __restrict__ kb_bf,
                       const float* __restrict__ sW0, const float* __restrict__ sb0,
                       float* __restrict__ out, Coefs cf) {
    __shared__ float smem[6144];
    float* a_t = smem;                    // [64][32]
    float* e_t = smem + 2048;             // [64][64]
    const int blk = blockIdx.x, j = threadIdx.x;
    const int b = blk / 144, rem = blk % 144;
    const int h0 = (rem / 6) * 32, c0 = (rem % 6) * 64;
    for (int i = j; i < TT * 32; i += 256) {
        int t = i >> 5, h = i & 31;
        a_t[t * 32 + h] = cf.ct[t] * bf2f(dh1p_bf[((size_t)(b * TT + t)) * HH + h0 + h]);
    }
    for (int i = j; i < TT * 64; i += 256) {
        int t = i >> 6, c = i & 63;
        e_t[t * 64 + c] = bf2f(kb_bf[((size_t)(b * TT + t)) * CC + c0 + c]);
    }
    __syncthreads();
    const int hi = j & 31, cb = (j >> 5) * 8;
    float acc[8] = {0, 0, 0, 0, 0, 0, 0, 0};
    for (int t = 0; t < TT; ++t) {
        float av = a_t[t * 32 + hi];
        #pragma unroll
        for (int m = 0; m < 8; ++m) acc[m] += av * e_t[t * 64 + cb + m];
    }
    const size_t idx = ((size_t)b * HH + h0 + hi) * CC + c0 + cb;
    const float4* w4 = (const float4*)(sW0 + idx);
    float4 wa = w4[0], wb = w4[1];
    float4 o0, o1;
    o0.x = cf.dfac * wa.x - acc[0]; o0.y = cf.dfac * wa.y - acc[1];
    o0.z = cf.dfac * wa.z - acc[2]; o0.w = cf.dfac * wa.w - acc[3];
    o1.x = cf.dfac * wb.x - acc[4]; o1.y = cf.dfac * wb.y - acc[5];
    o1.z = cf.dfac * wb.z - acc[6]; o1.w = cf.dfac * wb.w - acc[7];
    *(float4*)(out + O_NW0 + idx) = o0;
    *(float4*)(out + O_NW0 + idx + 4) = o1;
    if (c0 == 0 && j < 32) {              // nb0 for this h-range
        float s = 0.f;
        for (int t = 0; t < TT; ++t) s += a_t[t * 32 + j];
        out[O_NB0 + b * HH + h0 + j] = cf.dfac * sb0[b * HH + h0 + j] - s;
    }
}

extern "C" void kernel_launch(void* const* d_in, const int* in_sizes, int n_in,
                              void* d_out, int out_size, void* d_ws, size_t ws_size,
                              hipStream_t stream) {
    const float* x   = (const float*)d_in[0];
    const float* Wq  = (const float*)d_in[1];
    const float* bq  = (const float*)d_in[2];
    const float* Wk  = (const float*)d_in[3];
    const float* bk  = (const float*)d_in[4];
    const float* Wv  = (const float*)d_in[5];
    const float* bv  = (const float*)d_in[6];
    const float* Wo  = (const float*)d_in[7];
    const float* bo  = (const float*)d_in[8];
    const float* iq  = (const float*)d_in[9];
    const float* sW0 = (const float*)d_in[10];
    const float* sb0 = (const float*)d_in[11];
    const float* sW1 = (const float*)d_in[12];
    const float* sb1 = (const float*)d_in[13];

    float* fw = (float*)d_ws;
    float* qb   = fw;                 // 384
    float* hret = qb + 384;           // 1536
    float* pred = hret + 1536;        // 768
    float* vb   = pred + 768;         // 49152
    float* dsil = vb + 49152;         // 98304
    unsigned short* us = (unsigned short*)(dsil + 98304);
    unsigned short* kb_bf   = us;              // 49152
    unsigned short* h1_bf   = kb_bf + 49152;   // 98304
    unsigned short* dp_bf   = h1_bf + 98304;   // 49152
    unsigned short* dh1p_bf = dp_bf + 49152;   // 98304   (~1.2 MB total)

    // Closed-form scan coefficients (exact: the clipped seed gate cancels).
    Coefs cf;
    const double mom = 0.9, decay = 1.0 - 0.001, lr = 0.01;
    for (int s = 0; s < TT; ++s) {
        double sum = 0.0;
        for (int t = s; t < TT; ++t) sum += pow(decay, (double)(TT - 1 - t)) * pow(mom, (double)(t - s));
        cf.ct[s] = (float)(lr * (1.0 - mom) * sum);
    }
    cf.dfac = (float)pow(decay, (double)TT);

    k_qkv <<<dim3(48),  dim3(256), 0, stream>>>(x, Wk, bk, Wv, bv, Wq, bq, iq, kb_bf, vb, qb);
    k_h1  <<<dim3(120), dim3(256), 0, stream>>>(kb_bf, qb, sW0, sb0, h1_bf, dsil, hret);
    k_p   <<<dim3(60),  dim3(256), 0, stream>>>(h1_bf, hret, vb, sW1, sb1, dp_bf, pred);
    k_epi1<<<dim3(360), dim3(256), 0, stream>>>(dp_bf, h1_bf, dsil, sW1, sb1, pred, Wo, bo,
                                                dh1p_bf, (float*)d_out, cf);
    k_epi2<<<dim3(288), dim3(256), 0, stream>>>(dh1p_bf, kb_bf, sW0, sb0, (float*)d_out, cf);
}

// Round 8
// 142.011 us; speedup vs baseline: 3.1637x; 1.0264x over previous
//
#include <hip/hip_runtime.h>
#include <hip/hip_bf16.h>
#include <cmath>

#define BB 2
#define TT 64
#define CC 384
#define HH 768

// d_out flat offsets (fp32 elements): out, nW0, nb0, nW1, nb1
#define O_OUT 0
#define O_NW0 768
#define O_NB0 (768 + 589824)
#define O_NW1 (O_NB0 + 1536)
#define O_NB1 (O_NW1 + 589824)

struct Coefs { float ct[TT]; float dfac; };

typedef __attribute__((ext_vector_type(8))) short bf16x8;
typedef __attribute__((ext_vector_type(4))) float f32x4;

__device__ __forceinline__ float bf2f(unsigned short u) {
    union { unsigned int i; float f; } x; x.i = ((unsigned int)u) << 16; return x.f;
}
__device__ __forceinline__ unsigned short f2bf(float f) {
    union { float f; unsigned int i; } u; u.f = f;
    unsigned int x = u.i;
    unsigned int r = (x + 0x7fffu + ((x >> 16) & 1u)) >> 16;  // RNE
    return (unsigned short)r;
}
__device__ __forceinline__ f32x4 mfma16(bf16x8 a, bf16x8 b, f32x4 c) {
    return __builtin_amdgcn_mfma_f32_16x16x32_bf16(a, b, c, 0, 0, 0);
}
__device__ __forceinline__ bf16x8 ldbf8(const unsigned short* p) {
    return *(const bf16x8*)p;
}
__device__ __forceinline__ bf16x8 ldcvt8(const float* p) {
    float4 a = *(const float4*)p, b = *(const float4*)(p + 4);
    bf16x8 r;
    r[0] = (short)f2bf(a.x); r[1] = (short)f2bf(a.y); r[2] = (short)f2bf(a.z); r[3] = (short)f2bf(a.w);
    r[4] = (short)f2bf(b.x); r[5] = (short)f2bf(b.y); r[6] = (short)f2bf(b.z); r[7] = (short)f2bf(b.w);
    return r;
}
__device__ __forceinline__ bf16x8 ldcvt8s(const float* p, int stride) {
    bf16x8 r;
    #pragma unroll
    for (int i = 0; i < 8; ++i) r[i] = (short)f2bf(p[(size_t)i * stride]);
    return r;
}

// ---------------- K1: [x;iq] @ [Wk|Wv|Wq]^T, each weight read ONCE ----------------
// 204 waves = 51 blocks. w<192: mf=w%8 (x rows), npair=w/8 in [0,24) (Wk|Wv cols).
// w>=192: mf=8 (iq row), npair=24+(w-192) in [24,36) (Wq cols).
__global__ void __launch_bounds__(256) k_qkv(
        const float* __restrict__ x,
        const float* __restrict__ Wk, const float* __restrict__ bk,
        const float* __restrict__ Wv, const float* __restrict__ bv,
        const float* __restrict__ Wq, const float* __restrict__ bq,
        const float* __restrict__ iq,
        unsigned short* __restrict__ kb_bf, float* __restrict__ vb,
        float* __restrict__ qb) {
    const int blk = blockIdx.x, j = threadIdx.x;
    const int wid = j >> 6, L = j & 63;
    const int w = blk * 4 + wid;
    const int lrow = L & 15, kq = (L >> 4) * 8, quad = L >> 4;
    int mf, npair;
    if (w < 192) { mf = w % 8; npair = w / 8; }
    else         { mf = 8;     npair = 24 + (w - 192); }
    const float* Arow = (mf < 8) ? (x + (size_t)(mf * 16 + lrow) * CC) : iq;
    const int n0 = npair * 32 + lrow, n1 = n0 + 16;
    const float* B0 = (n0 < CC) ? (Wk + (size_t)n0 * CC)
                    : (n0 < 2 * CC) ? (Wv + (size_t)(n0 - CC) * CC)
                    : (Wq + (size_t)(n0 - 2 * CC) * CC);
    const float* B1 = (n1 < CC) ? (Wk + (size_t)n1 * CC)
                    : (n1 < 2 * CC) ? (Wv + (size_t)(n1 - CC) * CC)
                    : (Wq + (size_t)(n1 - 2 * CC) * CC);
    f32x4 acc0 = {0,0,0,0}, acc1 = {0,0,0,0};
    #pragma unroll 2
    for (int s = 0; s < CC / 32; ++s) {
        int k = s * 32 + kq;
        bf16x8 a = ldcvt8(Arow + k);
        bf16x8 b0 = ldcvt8(B0 + k), b1 = ldcvt8(B1 + k);
        acc0 = mfma16(a, b0, acc0); acc1 = mfma16(a, b1, acc1);
    }
    #pragma unroll
    for (int ni = 0; ni < 2; ++ni) {
        f32x4 acc = ni == 0 ? acc0 : acc1;
        int n = npair * 32 + ni * 16 + lrow;
        if (mf < 8) {
            #pragma unroll
            for (int r = 0; r < 4; ++r) {
                int m = mf * 16 + quad * 4 + r;
                float v = acc[r];
                if (n < CC) kb_bf[(size_t)m * CC + n] = f2bf(v + bk[n]);
                else        vb[(size_t)m * CC + (n - CC)] = v + bv[n - CC];
            }
        } else if (quad == 0) {
            qb[n - 2 * CC] = acc[0] + bq[n - 2 * CC];
        }
    }
}

// ---------------- K2: [kb;q] @ sW0^T -> h1/dsil/hret. sW0 read ONCE ----------------
// per b: 5 m-frags (kb 4 + q 1) x 24 n-pairs = 120 waves = 30 blocks; 60 total.
__global__ void __launch_bounds__(256) k_h1(
        const unsigned short* __restrict__ kb_bf, const float* __restrict__ qb,
        const float* __restrict__ sW0, const float* __restrict__ sb0,
        unsigned short* __restrict__ h1_bf, float* __restrict__ dsil,
        float* __restrict__ hret) {
    const int blk = blockIdx.x, j = threadIdx.x;
    const int b = blk / 30;
    const int wid = j >> 6, L = j & 63;
    const int w = (blk % 30) * 4 + wid;
    const int mf = w % 5, npair = w / 5;
    const int lrow = L & 15, kq = (L >> 4) * 8, quad = L >> 4;
    const unsigned short* Abf = kb_bf + (size_t)(b * TT + mf * 16 + lrow) * CC;
    const int n0 = npair * 32 + lrow;
    const float* B0 = sW0 + (size_t)(b * HH + n0) * CC;
    const float* B1 = B0 + 16 * CC;
    f32x4 acc0 = {0,0,0,0}, acc1 = {0,0,0,0};
    if (mf < 4) {
        #pragma unroll 2
        for (int s = 0; s < CC / 32; ++s) {
            int k = s * 32 + kq;
            bf16x8 a = ldbf8(Abf + k);
            bf16x8 b0 = ldcvt8(B0 + k), b1 = ldcvt8(B1 + k);
            acc0 = mfma16(a, b0, acc0); acc1 = mfma16(a, b1, acc1);
        }
    } else {
        #pragma unroll 2
        for (int s = 0; s < CC / 32; ++s) {
            int k = s * 32 + kq;
            bf16x8 a = ldcvt8(qb + k);
            bf16x8 b0 = ldcvt8(B0 + k), b1 = ldcvt8(B1 + k);
            acc0 = mfma16(a, b0, acc0); acc1 = mfma16(a, b1, acc1);
        }
    }
    #pragma unroll
    for (int ni = 0; ni < 2; ++ni) {
        f32x4 acc = ni == 0 ? acc0 : acc1;
        int n = npair * 32 + ni * 16 + lrow;
        float bias = sb0[b * HH + n];
        if (mf < 4) {
            #pragma unroll
            for (int r = 0; r < 4; ++r) {
                int t = mf * 16 + quad * 4 + r;
                float pre = acc[r] + bias;
                float sig = 1.f / (1.f + expf(-pre));
                size_t idx = (size_t)(b * TT + t) * HH + n;
                h1_bf[idx] = f2bf(pre * sig);
                dsil[idx]  = sig * (1.f + pre * (1.f - sig));
            }
        } else if (quad == 0) {
            float pre = acc[0] + bias;
            float sig = 1.f / (1.f + expf(-pre));
            hret[b * HH + n] = pre * sig;
        }
    }
}

// ---------------- K3: [h1;hret] @ sW1^T -> dp/pred. sW1 read ONCE ----------------
// per b: 5 m-frags x 12 n-pairs = 60 waves = 15 blocks; 30 total. K=768.
__global__ void __launch_bounds__(256) k_p(
        const unsigned short* __restrict__ h1_bf, const float* __restrict__ hret,
        const float* __restrict__ vb,
        const float* __restrict__ sW1, const float* __restrict__ sb1,
        unsigned short* __restrict__ dp_bf, float* __restrict__ pred) {
    const int blk = blockIdx.x, j = threadIdx.x;
    const int b = blk / 15;
    const int wid = j >> 6, L = j & 63;
    const int w = (blk % 15) * 4 + wid;
    const int mf = w % 5, npair = w / 5;
    const int lrow = L & 15, kq = (L >> 4) * 8, quad = L >> 4;
    const unsigned short* Abf = h1_bf + (size_t)(b * TT + mf * 16 + lrow) * HH;
    const float* Aq = hret + (size_t)b * HH;
    const int n0 = npair * 32 + lrow;
    const float* B0 = sW1 + (size_t)(b * CC + n0) * HH;
    const float* B1 = B0 + 16 * HH;
    f32x4 acc0 = {0,0,0,0}, acc1 = {0,0,0,0};
    if (mf < 4) {
        #pragma unroll 2
        for (int s = 0; s < HH / 32; ++s) {
            int k = s * 32 + kq;
            bf16x8 a = ldbf8(Abf + k);
            bf16x8 b0 = ldcvt8(B0 + k), b1 = ldcvt8(B1 + k);
            acc0 = mfma16(a, b0, acc0); acc1 = mfma16(a, b1, acc1);
        }
    } else {
        #pragma unroll 2
        for (int s = 0; s < HH / 32; ++s) {
            int k = s * 32 + kq;
            bf16x8 a = ldcvt8(Aq + k);
            bf16x8 b0 = ldcvt8(B0 + k), b1 = ldcvt8(B1 + k);
            acc0 = mfma16(a, b0, acc0); acc1 = mfma16(a, b1, acc1);
        }
    }
    #pragma unroll
    for (int ni = 0; ni < 2; ++ni) {
        f32x4 acc = ni == 0 ? acc0 : acc1;
        int n = npair * 32 + ni * 16 + lrow;
        float bias = sb1[b * CC + n];
        if (mf < 4) {
            #pragma unroll
            for (int r = 0; r < 4; ++r) {
                int t = mf * 16 + quad * 4 + r;
                size_t idx = (size_t)(b * TT + t) * CC + n;
                dp_bf[idx] = f2bf(acc[r] + bias - vb[idx]);
            }
        } else if (quad == 0) {
            pred[b * CC + n] = acc[0] + bias;
        }
    }
}

// ---------------- K4: dh1p MFMA + nW1 tiles (+nb1) + out GEMV ----------------
// blocks [0,48):    dh1p = (dp @ sW1cols) * dsil  — per b: 4 mf x 24 npair = 96 waves = 24 blocks
// blocks [48,336):  nW1 32c x 64h tiles; h0==0 blocks also write nb1
// blocks [336,384): out = pred @ Wo^T + bo
__global__ void __launch_bounds__(256) k_epi1(
        const unsigned short* __restrict__ dp_bf,
        const unsigned short* __restrict__ h1_bf,
        const float* __restrict__ dsil,
        const float* __restrict__ sW1, const float* __restrict__ sb1,
        const float* __restrict__ pred,
        const float* __restrict__ Wo, const float* __restrict__ bo,
        unsigned short* __restrict__ dh1p_bf,
        float* __restrict__ out, Coefs cf) {
    __shared__ float smem[6144];
    const int blk = blockIdx.x, j = threadIdx.x;
    if (blk < 48) {                       // dh1p MFMA
        const int b = blk / 24;
        const int wid = j >> 6, L = j & 63;
        const int w = (blk % 24) * 4 + wid;
        const int mf = w % 4, npair = w / 4;
        const int lrow = L & 15, kq = (L >> 4) * 8, quad = L >> 4;
        const unsigned short* Abf = dp_bf + (size_t)(b * TT + mf * 16 + lrow) * CC;
        const int n0 = npair * 32 + lrow, n1 = n0 + 16;
        const float* Bb = sW1 + (size_t)b * CC * HH;
        f32x4 acc0 = {0,0,0,0}, acc1 = {0,0,0,0};
        for (int s = 0; s < CC / 32; ++s) {
            int k = s * 32 + kq;
            bf16x8 a = ldbf8(Abf + k);
            bf16x8 b0 = ldcvt8s(Bb + (size_t)k * HH + n0, HH);
            bf16x8 b1 = ldcvt8s(Bb + (size_t)k * HH + n1, HH);
            acc0 = mfma16(a, b0, acc0); acc1 = mfma16(a, b1, acc1);
        }
        #pragma unroll
        for (int ni = 0; ni < 2; ++ni) {
            f32x4 acc = ni == 0 ? acc0 : acc1;
            int n = npair * 32 + ni * 16 + lrow;
            #pragma unroll
            for (int r = 0; r < 4; ++r) {
                int t = mf * 16 + quad * 4 + r;
                size_t idx = (size_t)(b * TT + t) * HH + n;
                dh1p_bf[idx] = f2bf(acc[r] * dsil[idx]);
            }
        }
    } else if (blk < 336) {               // nW1 tile 32c x 64h
        float* a_t = smem;                // [64][32]
        float* e_t = smem + 2048;         // [64][64]
        const int u = blk - 48;
        const int b = u / 144, rem = u % 144;
        const int c0 = (rem / 12) * 32, h0 = (rem % 12) * 64;
        for (int i = j; i < TT * 32; i += 256) {
            int t = i >> 5, c = i & 31;
            a_t[t * 32 + c] = cf.ct[t] * bf2f(dp_bf[((size_t)(b * TT + t)) * CC + c0 + c]);
        }
        for (int i = j; i < TT * 64; i += 256) {
            int t = i >> 6, h = i & 63;
            e_t[t * 64 + h] = bf2f(h1_bf[((size_t)(b * TT + t)) * HH + h0 + h]);
        }
        __syncthreads();
        const int ci = j & 31, hb = (j >> 5) * 8;
        float acc[8] = {0, 0, 0, 0, 0, 0, 0, 0};
        for (int t = 0; t < TT; ++t) {
            float av = a_t[t * 32 + ci];
            #pragma unroll
            for (int m = 0; m < 8; ++m) acc[m] += av * e_t[t * 64 + hb + m];
        }
        const size_t idx = ((size_t)b * CC + c0 + ci) * HH + h0 + hb;
        const float4* w4 = (const float4*)(sW1 + idx);
        float4 wa = w4[0], wb = w4[1];
        float4 o0, o1;
        o0.x = cf.dfac * wa.x - acc[0]; o0.y = cf.dfac * wa.y - acc[1];
        o0.z = cf.dfac * wa.z - acc[2]; o0.w = cf.dfac * wa.w - acc[3];
        o1.x = cf.dfac * wb.x - acc[4]; o1.y = cf.dfac * wb.y - acc[5];
        o1.z = cf.dfac * wb.z - acc[6]; o1.w = cf.dfac * wb.w - acc[7];
        *(float4*)(out + O_NW1 + idx) = o0;
        *(float4*)(out + O_NW1 + idx + 4) = o1;
        if (h0 == 0 && j < 32) {          // nb1 for this c-range
            float s = 0.f;
            for (int t = 0; t < TT; ++t) s += a_t[t * 32 + j];
            out[O_NB1 + b * CC + c0 + j] = cf.dfac * sb1[b * CC + c0 + j] - s;
        }
    } else {                              // out = pred@Wo^T + bo
        const int rb = blk - 336;
        const int b = rb / 24, nt = rb % 24;
        if (j < CC / 4) ((float4*)smem)[j] = ((const float4*)(pred + b * CC))[j];
        __syncthreads();
        const int nl = j & 15, ks = j >> 4;
        const int n = nt * 16 + nl;
        const float4* wr = (const float4*)(Wo + (size_t)n * CC + ks * 24);
        float s = 0.f;
        #pragma unroll
        for (int i = 0; i < 6; ++i) {
            float4 a = wr[i];
            const float* v = smem + ks * 24 + i * 4;
            s += a.x * v[0] + a.y * v[1] + a.z * v[2] + a.w * v[3];
        }
        smem[1024 + ks * 17 + nl] = s;
        __syncthreads();
        if (j < 16) {
            int n2 = nt * 16 + j;
            float acc = bo[n2];
            #pragma unroll
            for (int kk = 0; kk < 16; ++kk) acc += smem[1024 + kk * 17 + j];
            out[O_OUT + b * CC + n2] = acc;
        }
    }
}

// ---------------- K5: nW0 tiles (+nb0) ----------------
__global__ void __launch_bounds__(256) k_epi2(
        const unsigned short* __restrict__ dh1p_bf,
        const unsigned short* __restrict__ kb_bf,
        const float* __restrict__ sW0, const float* __restrict__ sb0,
        float* __restrict__ out, Coefs cf) {
    __shared__ float smem[6144];
    float* a_t = smem;                    // [64][32]
    float* e_t = smem + 2048;             // [64][64]
    const int blk = blockIdx.x, j = threadIdx.x;
    const int b = blk / 144, rem = blk % 144;
    const int h0 = (rem / 6) * 32, c0 = (rem % 6) * 64;
    for (int i = j; i < TT * 32; i += 256) {
        int t = i >> 5, h = i & 31;
        a_t[t * 32 + h] = cf.ct[t] * bf2f(dh1p_bf[((size_t)(b * TT + t)) * HH + h0 + h]);
    }
    for (int i = j; i < TT * 64; i += 256) {
        int t = i >> 6, c = i & 63;
        e_t[t * 64 + c] = bf2f(kb_bf[((size_t)(b * TT + t)) * CC + c0 + c]);
    }
    __syncthreads();
    const int hi = j & 31, cb = (j >> 5) * 8;
    float acc[8] = {0, 0, 0, 0, 0, 0, 0, 0};
    for (int t = 0; t < TT; ++t) {
        float av = a_t[t * 32 + hi];
        #pragma unroll
        for (int m = 0; m < 8; ++m) acc[m] += av * e_t[t * 64 + cb + m];
    }
    const size_t idx = ((size_t)b * HH + h0 + hi) * CC + c0 + cb;
    const float4* w4 = (const float4*)(sW0 + idx);
    float4 wa = w4[0], wb = w4[1];
    float4 o0, o1;
    o0.x = cf.dfac * wa.x - acc[0]; o0.y = cf.dfac * wa.y - acc[1];
    o0.z = cf.dfac * wa.z - acc[2]; o0.w = cf.dfac * wa.w - acc[3];
    o1.x = cf.dfac * wb.x - acc[4]; o1.y = cf.dfac * wb.y - acc[5];
    o1.z = cf.dfac * wb.z - acc[6]; o1.w = cf.dfac * wb.w - acc[7];
    *(float4*)(out + O_NW0 + idx) = o0;
    *(float4*)(out + O_NW0 + idx + 4) = o1;
    if (c0 == 0 && j < 32) {              // nb0 for this h-range
        float s = 0.f;
        for (int t = 0; t < TT; ++t) s += a_t[t * 32 + j];
        out[O_NB0 + b * HH + h0 + j] = cf.dfac * sb0[b * HH + h0 + j] - s;
    }
}

extern "C" void kernel_launch(void* const* d_in, const int* in_sizes, int n_in,
                              void* d_out, int out_size, void* d_ws, size_t ws_size,
                              hipStream_t stream) {
    const float* x   = (const float*)d_in[0];
    const float* Wq  = (const float*)d_in[1];
    const float* bq  = (const float*)d_in[2];
    const float* Wk  = (const float*)d_in[3];
    const float* bk  = (const float*)d_in[4];
    const float* Wv  = (const float*)d_in[5];
    const float* bv  = (const float*)d_in[6];
    const float* Wo  = (const float*)d_in[7];
    const float* bo  = (const float*)d_in[8];
    const float* iq  = (const float*)d_in[9];
    const float* sW0 = (const float*)d_in[10];
    const float* sb0 = (const float*)d_in[11];
    const float* sW1 = (const float*)d_in[12];
    const float* sb1 = (const float*)d_in[13];

    float* fw = (float*)d_ws;
    float* qb   = fw;                 // 384
    float* hret = qb + 384;           // 1536
    float* pred = hret + 1536;        // 768
    float* vb   = pred + 768;         // 49152
    float* dsil = vb + 49152;         // 98304
    unsigned short* us = (unsigned short*)(dsil + 98304);
    unsigned short* kb_bf   = us;              // 49152
    unsigned short* h1_bf   = kb_bf + 49152;   // 98304
    unsigned short* dp_bf   = h1_bf + 98304;   // 49152
    unsigned short* dh1p_bf = dp_bf + 49152;   // 98304   (~1.2 MB total)

    // Closed-form scan coefficients (exact: the clipped seed gate cancels).
    Coefs cf;
    const double mom = 0.9, decay = 1.0 - 0.001, lr = 0.01;
    for (int s = 0; s < TT; ++s) {
        double sum = 0.0;
        for (int t = s; t < TT; ++t) sum += pow(decay, (double)(TT - 1 - t)) * pow(mom, (double)(t - s));
        cf.ct[s] = (float)(lr * (1.0 - mom) * sum);
    }
    cf.dfac = (float)pow(decay, (double)TT);

    k_qkv <<<dim3(51),  dim3(256), 0, stream>>>(x, Wk, bk, Wv, bv, Wq, bq, iq, kb_bf, vb, qb);
    k_h1  <<<dim3(60),  dim3(256), 0, stream>>>(kb_bf, qb, sW0, sb0, h1_bf, dsil, hret);
    k_p   <<<dim3(30),  dim3(256), 0, stream>>>(h1_bf, hret, vb, sW1, sb1, dp_bf, pred);
    k_epi1<<<dim3(384), dim3(256), 0, stream>>>(dp_bf, h1_bf, dsil, sW1, sb1, pred, Wo, bo,
                                                dh1p_bf, (float*)d_out, cf);
    k_epi2<<<dim3(288), dim3(256), 0, stream>>>(dh1p_bf, kb_bf, sW0, sb0, (float*)d_out, cf);
}

// Round 9
// 138.216 us; speedup vs baseline: 3.2506x; 1.0275x over previous
//
#include <hip/hip_runtime.h>
#include <hip/hip_bf16.h>
#include <cmath>

#define BB 2
#define TT 64
#define CC 384
#define HH 768

// d_out flat offsets (fp32 elements): out, nW0, nb0, nW1, nb1
#define O_OUT 0
#define O_NW0 768
#define O_NB0 (768 + 589824)
#define O_NW1 (O_NB0 + 1536)
#define O_NB1 (O_NW1 + 589824)

struct Coefs { float ct[TT]; float dfac; };

typedef __attribute__((ext_vector_type(8))) short bf16x8;
typedef __attribute__((ext_vector_type(4))) float f32x4;

__device__ __forceinline__ float bf2f(unsigned short u) {
    union { unsigned int i; float f; } x; x.i = ((unsigned int)u) << 16; return x.f;
}
__device__ __forceinline__ unsigned short f2bf(float f) {
    union { float f; unsigned int i; } u; u.f = f;
    unsigned int x = u.i;
    unsigned int r = (x + 0x7fffu + ((x >> 16) & 1u)) >> 16;  // RNE
    return (unsigned short)r;
}
__device__ __forceinline__ f32x4 mfma16(bf16x8 a, bf16x8 b, f32x4 c) {
    return __builtin_amdgcn_mfma_f32_16x16x32_bf16(a, b, c, 0, 0, 0);
}
__device__ __forceinline__ bf16x8 ldbf8(const unsigned short* p) {
    return *(const bf16x8*)p;
}
__device__ __forceinline__ bf16x8 ldcvt8(const float* p) {
    float4 a = *(const float4*)p, b = *(const float4*)(p + 4);
    bf16x8 r;
    r[0] = (short)f2bf(a.x); r[1] = (short)f2bf(a.y); r[2] = (short)f2bf(a.z); r[3] = (short)f2bf(a.w);
    r[4] = (short)f2bf(b.x); r[5] = (short)f2bf(b.y); r[6] = (short)f2bf(b.z); r[7] = (short)f2bf(b.w);
    return r;
}
__device__ __forceinline__ bf16x8 ldcvt8s(const float* p, int stride) {
    bf16x8 r;
    #pragma unroll
    for (int i = 0; i < 8; ++i) r[i] = (short)f2bf(p[(size_t)i * stride]);
    return r;
}

// ---------------- K1: [x;iq] @ [Wk|Wv|Wq]^T  + L3-warm blocks for sW0/sW1/Wo ----------------
// blocks [0,51): MFMA. 204 waves: w<192: mf=w%8 (x rows), npair=w/8 (Wk|Wv); w>=192: iq row, Wq.
// blocks [51,563): warm-read sW0, sW1, Wo into L3 (concurrent with MFMA blocks).
__global__ void __launch_bounds__(256) k_qkv(
        const float* __restrict__ x,
        const float* __restrict__ Wk, const float* __restrict__ bk,
        const float* __restrict__ Wv, const float* __restrict__ bv,
        const float* __restrict__ Wq, const float* __restrict__ bq,
        const float* __restrict__ iq,
        const float* __restrict__ sW0, const float* __restrict__ sW1,
        const float* __restrict__ Wo,
        unsigned short* __restrict__ kb_bf, float* __restrict__ vb,
        float* __restrict__ qb, float* __restrict__ warm_sink) {
    const int blk = blockIdx.x, j = threadIdx.x;
    if (blk >= 51) {   // warm path: stream 10 MB of weights to pull them into L3
        int t = (blk - 51) * 256 + j;     // 131072 threads
        float acc = 0.f;
        for (int g = t; g < 184320; g += 512 * 256) {
            const float4* src; int off;
            if      (g < 73728)  { src = (const float4*)sW0; off = g; }
            else if (g < 147456) { src = (const float4*)sW1; off = g - 73728; }
            else                 { src = (const float4*)Wo;  off = g - 147456; }
            float4 v = src[off];
            acc += v.x + v.y + v.z + v.w;
        }
        warm_sink[t] = acc;
        return;
    }
    const int wid = j >> 6, L = j & 63;
    const int w = blk * 4 + wid;
    const int lrow = L & 15, kq = (L >> 4) * 8, quad = L >> 4;
    int mf, npair;
    if (w < 192) { mf = w % 8; npair = w / 8; }
    else         { mf = 8;     npair = 24 + (w - 192); }
    const float* Arow = (mf < 8) ? (x + (size_t)(mf * 16 + lrow) * CC) : iq;
    const int n0 = npair * 32 + lrow, n1 = n0 + 16;
    const float* B0 = (n0 < CC) ? (Wk + (size_t)n0 * CC)
                    : (n0 < 2 * CC) ? (Wv + (size_t)(n0 - CC) * CC)
                    : (Wq + (size_t)(n0 - 2 * CC) * CC);
    const float* B1 = (n1 < CC) ? (Wk + (size_t)n1 * CC)
                    : (n1 < 2 * CC) ? (Wv + (size_t)(n1 - CC) * CC)
                    : (Wq + (size_t)(n1 - 2 * CC) * CC);
    f32x4 acc0 = {0,0,0,0}, acc1 = {0,0,0,0};
    #pragma unroll 2
    for (int s = 0; s < CC / 32; ++s) {
        int k = s * 32 + kq;
        bf16x8 a = ldcvt8(Arow + k);
        bf16x8 b0 = ldcvt8(B0 + k), b1 = ldcvt8(B1 + k);
        acc0 = mfma16(a, b0, acc0); acc1 = mfma16(a, b1, acc1);
    }
    #pragma unroll
    for (int ni = 0; ni < 2; ++ni) {
        f32x4 acc = ni == 0 ? acc0 : acc1;
        int n = npair * 32 + ni * 16 + lrow;
        if (mf < 8) {
            #pragma unroll
            for (int r = 0; r < 4; ++r) {
                int m = mf * 16 + quad * 4 + r;
                float v = acc[r];
                if (n < CC) kb_bf[(size_t)m * CC + n] = f2bf(v + bk[n]);
                else        vb[(size_t)m * CC + (n - CC)] = v + bv[n - CC];
            }
        } else if (quad == 0) {
            qb[n - 2 * CC] = acc[0] + bq[n - 2 * CC];
        }
    }
}

// ---------------- K2: [kb;q] @ sW0^T -> h1/dsil/hret (sW0 read once, L3-warm) ----------------
__global__ void __launch_bounds__(256) k_h1(
        const unsigned short* __restrict__ kb_bf, const float* __restrict__ qb,
        const float* __restrict__ sW0, const float* __restrict__ sb0,
        unsigned short* __restrict__ h1_bf, float* __restrict__ dsil,
        float* __restrict__ hret) {
    const int blk = blockIdx.x, j = threadIdx.x;
    const int b = blk / 30;
    const int wid = j >> 6, L = j & 63;
    const int w = (blk % 30) * 4 + wid;
    const int mf = w % 5, npair = w / 5;
    const int lrow = L & 15, kq = (L >> 4) * 8, quad = L >> 4;
    const unsigned short* Abf = kb_bf + (size_t)(b * TT + mf * 16 + lrow) * CC;
    const int n0 = npair * 32 + lrow;
    const float* B0 = sW0 + (size_t)(b * HH + n0) * CC;
    const float* B1 = B0 + 16 * CC;
    f32x4 acc0 = {0,0,0,0}, acc1 = {0,0,0,0};
    if (mf < 4) {
        #pragma unroll 2
        for (int s = 0; s < CC / 32; ++s) {
            int k = s * 32 + kq;
            bf16x8 a = ldbf8(Abf + k);
            bf16x8 b0 = ldcvt8(B0 + k), b1 = ldcvt8(B1 + k);
            acc0 = mfma16(a, b0, acc0); acc1 = mfma16(a, b1, acc1);
        }
    } else {
        #pragma unroll 2
        for (int s = 0; s < CC / 32; ++s) {
            int k = s * 32 + kq;
            bf16x8 a = ldcvt8(qb + k);
            bf16x8 b0 = ldcvt8(B0 + k), b1 = ldcvt8(B1 + k);
            acc0 = mfma16(a, b0, acc0); acc1 = mfma16(a, b1, acc1);
        }
    }
    #pragma unroll
    for (int ni = 0; ni < 2; ++ni) {
        f32x4 acc = ni == 0 ? acc0 : acc1;
        int n = npair * 32 + ni * 16 + lrow;
        float bias = sb0[b * HH + n];
        if (mf < 4) {
            #pragma unroll
            for (int r = 0; r < 4; ++r) {
                int t = mf * 16 + quad * 4 + r;
                float pre = acc[r] + bias;
                float sig = 1.f / (1.f + expf(-pre));
                size_t idx = (size_t)(b * TT + t) * HH + n;
                h1_bf[idx] = f2bf(pre * sig);
                dsil[idx]  = sig * (1.f + pre * (1.f - sig));
            }
        } else if (quad == 0) {
            float pre = acc[0] + bias;
            float sig = 1.f / (1.f + expf(-pre));
            hret[b * HH + n] = pre * sig;
        }
    }
}

// ---------------- K3: [h1;hret] @ sW1^T -> dp/pred (sW1 read once, L3-warm) ----------------
__global__ void __launch_bounds__(256) k_p(
        const unsigned short* __restrict__ h1_bf, const float* __restrict__ hret,
        const float* __restrict__ vb,
        const float* __restrict__ sW1, const float* __restrict__ sb1,
        unsigned short* __restrict__ dp_bf, float* __restrict__ pred) {
    const int blk = blockIdx.x, j = threadIdx.x;
    const int b = blk / 15;
    const int wid = j >> 6, L = j & 63;
    const int w = (blk % 15) * 4 + wid;
    const int mf = w % 5, npair = w / 5;
    const int lrow = L & 15, kq = (L >> 4) * 8, quad = L >> 4;
    const unsigned short* Abf = h1_bf + (size_t)(b * TT + mf * 16 + lrow) * HH;
    const float* Aq = hret + (size_t)b * HH;
    const int n0 = npair * 32 + lrow;
    const float* B0 = sW1 + (size_t)(b * CC + n0) * HH;
    const float* B1 = B0 + 16 * HH;
    f32x4 acc0 = {0,0,0,0}, acc1 = {0,0,0,0};
    if (mf < 4) {
        #pragma unroll 2
        for (int s = 0; s < HH / 32; ++s) {
            int k = s * 32 + kq;
            bf16x8 a = ldbf8(Abf + k);
            bf16x8 b0 = ldcvt8(B0 + k), b1 = ldcvt8(B1 + k);
            acc0 = mfma16(a, b0, acc0); acc1 = mfma16(a, b1, acc1);
        }
    } else {
        #pragma unroll 2
        for (int s = 0; s < HH / 32; ++s) {
            int k = s * 32 + kq;
            bf16x8 a = ldcvt8(Aq + k);
            bf16x8 b0 = ldcvt8(B0 + k), b1 = ldcvt8(B1 + k);
            acc0 = mfma16(a, b0, acc0); acc1 = mfma16(a, b1, acc1);
        }
    }
    #pragma unroll
    for (int ni = 0; ni < 2; ++ni) {
        f32x4 acc = ni == 0 ? acc0 : acc1;
        int n = npair * 32 + ni * 16 + lrow;
        float bias = sb1[b * CC + n];
        if (mf < 4) {
            #pragma unroll
            for (int r = 0; r < 4; ++r) {
                int t = mf * 16 + quad * 4 + r;
                size_t idx = (size_t)(b * TT + t) * CC + n;
                dp_bf[idx] = f2bf(acc[r] + bias - vb[idx]);
            }
        } else if (quad == 0) {
            pred[b * CC + n] = acc[0] + bias;
        }
    }
}

// ---------------- K4: everything else in one kernel ----------------
// blocks [0,288):   nW1 32c x 64h tiles (+nb1 on h0==0)
// blocks [288,576): nW0 32h x 64c tiles, dh1p slice recomputed INLINE via MFMA (+nb0 on c0==0)
// blocks [576,624): out = pred @ Wo^T + bo
__global__ void __launch_bounds__(256) k_epi(
        const unsigned short* __restrict__ dp_bf,
        const unsigned short* __restrict__ h1_bf,
        const unsigned short* __restrict__ kb_bf,
        const float* __restrict__ dsil,
        const float* __restrict__ sW0, const float* __restrict__ sb0,
        const float* __restrict__ sW1, const float* __restrict__ sb1,
        const float* __restrict__ pred,
        const float* __restrict__ Wo, const float* __restrict__ bo,
        float* __restrict__ out, Coefs cf) {
    __shared__ float smem[6144];
    const int blk = blockIdx.x, j = threadIdx.x;
    if (blk < 288) {                      // nW1 tile
        float* a_t = smem;                // [64][32]
        float* e_t = smem + 2048;         // [64][64]
        const int b = blk / 144, rem = blk % 144;
        const int c0 = (rem / 12) * 32, h0 = (rem % 12) * 64;
        for (int i = j; i < TT * 32; i += 256) {
            int t = i >> 5, c = i & 31;
            a_t[t * 32 + c] = cf.ct[t] * bf2f(dp_bf[((size_t)(b * TT + t)) * CC + c0 + c]);
        }
        for (int i = j; i < TT * 64; i += 256) {
            int t = i >> 6, h = i & 63;
            e_t[t * 64 + h] = bf2f(h1_bf[((size_t)(b * TT + t)) * HH + h0 + h]);
        }
        __syncthreads();
        const int ci = j & 31, hb = (j >> 5) * 8;
        float acc[8] = {0, 0, 0, 0, 0, 0, 0, 0};
        for (int t = 0; t < TT; ++t) {
            float av = a_t[t * 32 + ci];
            #pragma unroll
            for (int m = 0; m < 8; ++m) acc[m] += av * e_t[t * 64 + hb + m];
        }
        const size_t idx = ((size_t)b * CC + c0 + ci) * HH + h0 + hb;
        const float4* w4 = (const float4*)(sW1 + idx);
        float4 wa = w4[0], wb = w4[1];
        float4 o0, o1;
        o0.x = cf.dfac * wa.x - acc[0]; o0.y = cf.dfac * wa.y - acc[1];
        o0.z = cf.dfac * wa.z - acc[2]; o0.w = cf.dfac * wa.w - acc[3];
        o1.x = cf.dfac * wb.x - acc[4]; o1.y = cf.dfac * wb.y - acc[5];
        o1.z = cf.dfac * wb.z - acc[6]; o1.w = cf.dfac * wb.w - acc[7];
        *(float4*)(out + O_NW1 + idx) = o0;
        *(float4*)(out + O_NW1 + idx + 4) = o1;
        if (h0 == 0 && j < 32) {
            float s = 0.f;
            for (int t = 0; t < TT; ++t) s += a_t[t * 32 + j];
            out[O_NB1 + b * CC + c0 + j] = cf.dfac * sb1[b * CC + c0 + j] - s;
        }
    } else if (blk < 576) {               // nW0 tile with inline dh1p
        float* a_t = smem;                // [64][32]
        float* e_t = smem + 2048;         // [64][64]
        const int u = blk - 288;
        const int b = u / 144, rem = u % 144;
        const int h0 = (rem / 6) * 32, c0 = (rem % 6) * 64;
        // e_t = kb slice
        for (int i = j; i < TT * 64; i += 256) {
            int t = i >> 6, c = i & 63;
            e_t[t * 64 + c] = bf2f(kb_bf[((size_t)(b * TT + t)) * CC + c0 + c]);
        }
        // a_t[t][hl] = ct[t] * dh1p[t, h0+hl] via MFMA: dh1 = dp @ sW1[:, h0:h0+32]
        const int wid = j >> 6, L = j & 63;
        const int lrow = L & 15, kq = (L >> 4) * 8, quad = L >> 4;
        const unsigned short* Abf = dp_bf + (size_t)(b * TT + wid * 16 + lrow) * CC;
        const float* Bb = sW1 + (size_t)b * CC * HH;
        const int n0 = h0 + lrow, n1 = h0 + 16 + lrow;
        f32x4 acc0 = {0,0,0,0}, acc1 = {0,0,0,0};
        for (int s = 0; s < CC / 32; ++s) {
            int k = s * 32 + kq;
            bf16x8 a = ldbf8(Abf + k);
            bf16x8 b0 = ldcvt8s(Bb + (size_t)k * HH + n0, HH);
            bf16x8 b1 = ldcvt8s(Bb + (size_t)k * HH + n1, HH);
            acc0 = mfma16(a, b0, acc0); acc1 = mfma16(a, b1, acc1);
        }
        #pragma unroll
        for (int ni = 0; ni < 2; ++ni) {
            f32x4 acc = ni == 0 ? acc0 : acc1;
            int hl = ni * 16 + lrow;
            #pragma unroll
            for (int r = 0; r < 4; ++r) {
                int t = wid * 16 + quad * 4 + r;
                float ds = dsil[(size_t)(b * TT + t) * HH + h0 + hl];
                a_t[t * 32 + hl] = cf.ct[t] * (acc[r] * ds);
            }
        }
        __syncthreads();
        const int hi = j & 31, cb = (j >> 5) * 8;
        float acc[8] = {0, 0, 0, 0, 0, 0, 0, 0};
        for (int t = 0; t < TT; ++t) {
            float av = a_t[t * 32 + hi];
            #pragma unroll
            for (int m = 0; m < 8; ++m) acc[m] += av * e_t[t * 64 + cb + m];
        }
        const size_t idx = ((size_t)b * HH + h0 + hi) * CC + c0 + cb;
        const float4* w4 = (const float4*)(sW0 + idx);
        float4 wa = w4[0], wb = w4[1];
        float4 o0, o1;
        o0.x = cf.dfac * wa.x - acc[0]; o0.y = cf.dfac * wa.y - acc[1];
        o0.z = cf.dfac * wa.z - acc[2]; o0.w = cf.dfac * wa.w - acc[3];
        o1.x = cf.dfac * wb.x - acc[4]; o1.y = cf.dfac * wb.y - acc[5];
        o1.z = cf.dfac * wb.z - acc[6]; o1.w = cf.dfac * wb.w - acc[7];
        *(float4*)(out + O_NW0 + idx) = o0;
        *(float4*)(out + O_NW0 + idx + 4) = o1;
        if (c0 == 0 && j < 32) {
            float s = 0.f;
            for (int t = 0; t < TT; ++t) s += a_t[t * 32 + j];
            out[O_NB0 + b * HH + h0 + j] = cf.dfac * sb0[b * HH + h0 + j] - s;
        }
    } else {                              // out = pred@Wo^T + bo
        const int rb = blk - 576;
        const int b = rb / 24, nt = rb % 24;
        if (j < CC / 4) ((float4*)smem)[j] = ((const float4*)(pred + b * CC))[j];
        __syncthreads();
        const int nl = j & 15, ks = j >> 4;
        const int n = nt * 16 + nl;
        const float4* wr = (const float4*)(Wo + (size_t)n * CC + ks * 24);
        float s = 0.f;
        #pragma unroll
        for (int i = 0; i < 6; ++i) {
            float4 a = wr[i];
            const float* v = smem + ks * 24 + i * 4;
            s += a.x * v[0] + a.y * v[1] + a.z * v[2] + a.w * v[3];
        }
        smem[1024 + ks * 17 + nl] = s;
        __syncthreads();
        if (j < 16) {
            int n2 = nt * 16 + j;
            float acc = bo[n2];
            #pragma unroll
            for (int kk = 0; kk < 16; ++kk) acc += smem[1024 + kk * 17 + j];
            out[O_OUT + b * CC + n2] = acc;
        }
    }
}

extern "C" void kernel_launch(void* const* d_in, const int* in_sizes, int n_in,
                              void* d_out, int out_size, void* d_ws, size_t ws_size,
                              hipStream_t stream) {
    const float* x   = (const float*)d_in[0];
    const float* Wq  = (const float*)d_in[1];
    const float* bq  = (const float*)d_in[2];
    const float* Wk  = (const float*)d_in[3];
    const float* bk  = (const float*)d_in[4];
    const float* Wv  = (const float*)d_in[5];
    const float* bv  = (const float*)d_in[6];
    const float* Wo  = (const float*)d_in[7];
    const float* bo  = (const float*)d_in[8];
    const float* iq  = (const float*)d_in[9];
    const float* sW0 = (const float*)d_in[10];
    const float* sb0 = (const float*)d_in[11];
    const float* sW1 = (const float*)d_in[12];
    const float* sb1 = (const float*)d_in[13];

    float* fw = (float*)d_ws;
    float* qb   = fw;                 // 384
    float* hret = qb + 384;           // 1536
    float* pred = hret + 1536;        // 768
    float* vb   = pred + 768;         // 49152
    float* dsil = vb + 49152;         // 98304
    float* warm = dsil + 98304;       // 131072
    unsigned short* us = (unsigned short*)(warm + 131072);
    unsigned short* kb_bf = us;              // 49152
    unsigned short* h1_bf = kb_bf + 49152;   // 98304
    unsigned short* dp_bf = h1_bf + 98304;   // 49152

    // Closed-form scan coefficients (exact: the clipped seed gate cancels).
    Coefs cf;
    const double mom = 0.9, decay = 1.0 - 0.001, lr = 0.01;
    for (int s = 0; s < TT; ++s) {
        double sum = 0.0;
        for (int t = s; t < TT; ++t) sum += pow(decay, (double)(TT - 1 - t)) * pow(mom, (double)(t - s));
        cf.ct[s] = (float)(lr * (1.0 - mom) * sum);
    }
    cf.dfac = (float)pow(decay, (double)TT);

    k_qkv<<<dim3(563), dim3(256), 0, stream>>>(x, Wk, bk, Wv, bv, Wq, bq, iq, sW0, sW1, Wo,
                                               kb_bf, vb, qb, warm);
    k_h1 <<<dim3(60),  dim3(256), 0, stream>>>(kb_bf, qb, sW0, sb0, h1_bf, dsil, hret);
    k_p  <<<dim3(30),  dim3(256), 0, stream>>>(h1_bf, hret, vb, sW1, sb1, dp_bf, pred);
    k_epi<<<dim3(624), dim3(256), 0, stream>>>(dp_bf, h1_bf, kb_bf, dsil, sW0, sb0, sW1, sb1,
                                               pred, Wo, bo, (float*)d_out, cf);
}

// Round 10
// 136.297 us; speedup vs baseline: 3.2964x; 1.0141x over previous
//
#include <hip/hip_runtime.h>
#include <hip/hip_bf16.h>
#include <cmath>

#define BB 2
#define TT 64
#define CC 384
#define HH 768

// d_out flat offsets (fp32 elements): out, nW0, nb0, nW1, nb1
#define O_OUT 0
#define O_NW0 768
#define O_NB0 (768 + 589824)
#define O_NW1 (O_NB0 + 1536)
#define O_NB1 (O_NW1 + 589824)

struct Coefs { float ct[TT]; float dfac; };

typedef __attribute__((ext_vector_type(8))) short bf16x8;
typedef __attribute__((ext_vector_type(4))) float f32x4;

__device__ __forceinline__ float bf2f(unsigned short u) {
    union { unsigned int i; float f; } x; x.i = ((unsigned int)u) << 16; return x.f;
}
__device__ __forceinline__ unsigned short f2bf(float f) {
    union { float f; unsigned int i; } u; u.f = f;
    unsigned int x = u.i;
    unsigned int r = (x + 0x7fffu + ((x >> 16) & 1u)) >> 16;  // RNE
    return (unsigned short)r;
}
__device__ __forceinline__ f32x4 mfma16(bf16x8 a, bf16x8 b, f32x4 c) {
    return __builtin_amdgcn_mfma_f32_16x16x32_bf16(a, b, c, 0, 0, 0);
}
__device__ __forceinline__ bf16x8 ldbf8(const unsigned short* p) {
    return *(const bf16x8*)p;
}
__device__ __forceinline__ bf16x8 ldcvt8(const float* p) {
    float4 a = *(const float4*)p, b = *(const float4*)(p + 4);
    bf16x8 r;
    r[0] = (short)f2bf(a.x); r[1] = (short)f2bf(a.y); r[2] = (short)f2bf(a.z); r[3] = (short)f2bf(a.w);
    r[4] = (short)f2bf(b.x); r[5] = (short)f2bf(b.y); r[6] = (short)f2bf(b.z); r[7] = (short)f2bf(b.w);
    return r;
}

// ---------------- K1: [x;iq] @ [Wk|Wv|Wq]^T  + L3-warm blocks for sW0/sW1/Wo ----------------
__global__ void __launch_bounds__(256) k_qkv(
        const float* __restrict__ x,
        const float* __restrict__ Wk, const float* __restrict__ bk,
        const float* __restrict__ Wv, const float* __restrict__ bv,
        const float* __restrict__ Wq, const float* __restrict__ bq,
        const float* __restrict__ iq,
        const float* __restrict__ sW0, const float* __restrict__ sW1,
        const float* __restrict__ Wo,
        unsigned short* __restrict__ kb_bf, float* __restrict__ vb,
        float* __restrict__ qb, float* __restrict__ warm_sink) {
    const int blk = blockIdx.x, j = threadIdx.x;
    if (blk >= 51) {   // warm path: stream 10 MB of weights to pull them into L3
        int t = (blk - 51) * 256 + j;     // 131072 threads
        float acc = 0.f;
        for (int g = t; g < 184320; g += 512 * 256) {
            const float4* src; int off;
            if      (g < 73728)  { src = (const float4*)sW0; off = g; }
            else if (g < 147456) { src = (const float4*)sW1; off = g - 73728; }
            else                 { src = (const float4*)Wo;  off = g - 147456; }
            float4 v = src[off];
            acc += v.x + v.y + v.z + v.w;
        }
        if (acc != acc) warm_sink[0] = acc;   // never taken (finite data); keeps loads live
        return;
    }
    const int wid = j >> 6, L = j & 63;
    const int w = blk * 4 + wid;
    const int lrow = L & 15, kq = (L >> 4) * 8, quad = L >> 4;
    int mf, npair;
    if (w < 192) { mf = w % 8; npair = w / 8; }
    else         { mf = 8;     npair = 24 + (w - 192); }
    const float* Arow = (mf < 8) ? (x + (size_t)(mf * 16 + lrow) * CC) : iq;
    const int n0 = npair * 32 + lrow, n1 = n0 + 16;
    const float* B0 = (n0 < CC) ? (Wk + (size_t)n0 * CC)
                    : (n0 < 2 * CC) ? (Wv + (size_t)(n0 - CC) * CC)
                    : (Wq + (size_t)(n0 - 2 * CC) * CC);
    const float* B1 = (n1 < CC) ? (Wk + (size_t)n1 * CC)
                    : (n1 < 2 * CC) ? (Wv + (size_t)(n1 - CC) * CC)
                    : (Wq + (size_t)(n1 - 2 * CC) * CC);
    f32x4 acc0 = {0,0,0,0}, acc1 = {0,0,0,0};
    #pragma unroll 2
    for (int s = 0; s < CC / 32; ++s) {
        int k = s * 32 + kq;
        bf16x8 a = ldcvt8(Arow + k);
        bf16x8 b0 = ldcvt8(B0 + k), b1 = ldcvt8(B1 + k);
        acc0 = mfma16(a, b0, acc0); acc1 = mfma16(a, b1, acc1);
    }
    #pragma unroll
    for (int ni = 0; ni < 2; ++ni) {
        f32x4 acc = ni == 0 ? acc0 : acc1;
        int n = npair * 32 + ni * 16 + lrow;
        if (mf < 8) {
            #pragma unroll
            for (int r = 0; r < 4; ++r) {
                int m = mf * 16 + quad * 4 + r;
                float v = acc[r];
                if (n < CC) kb_bf[(size_t)m * CC + n] = f2bf(v + bk[n]);
                else        vb[(size_t)m * CC + (n - CC)] = v + bv[n - CC];
            }
        } else if (quad == 0) {
            qb[n - 2 * CC] = acc[0] + bq[n - 2 * CC];
        }
    }
}

// ---------------- K2: [kb;q] @ sW0^T -> h1/dsil/hret (sW0 read once, L3-warm) ----------------
__global__ void __launch_bounds__(256) k_h1(
        const unsigned short* __restrict__ kb_bf, const float* __restrict__ qb,
        const float* __restrict__ sW0, const float* __restrict__ sb0,
        unsigned short* __restrict__ h1_bf, float* __restrict__ dsil,
        float* __restrict__ hret) {
    const int blk = blockIdx.x, j = threadIdx.x;
    const int b = blk / 30;
    const int wid = j >> 6, L = j & 63;
    const int w = (blk % 30) * 4 + wid;
    const int mf = w % 5, npair = w / 5;
    const int lrow = L & 15, kq = (L >> 4) * 8, quad = L >> 4;
    const unsigned short* Abf = kb_bf + (size_t)(b * TT + mf * 16 + lrow) * CC;
    const int n0 = npair * 32 + lrow;
    const float* B0 = sW0 + (size_t)(b * HH + n0) * CC;
    const float* B1 = B0 + 16 * CC;
    f32x4 acc0 = {0,0,0,0}, acc1 = {0,0,0,0};
    if (mf < 4) {
        #pragma unroll 2
        for (int s = 0; s < CC / 32; ++s) {
            int k = s * 32 + kq;
            bf16x8 a = ldbf8(Abf + k);
            bf16x8 b0 = ldcvt8(B0 + k), b1 = ldcvt8(B1 + k);
            acc0 = mfma16(a, b0, acc0); acc1 = mfma16(a, b1, acc1);
        }
    } else {
        #pragma unroll 2
        for (int s = 0; s < CC / 32; ++s) {
            int k = s * 32 + kq;
            bf16x8 a = ldcvt8(qb + k);
            bf16x8 b0 = ldcvt8(B0 + k), b1 = ldcvt8(B1 + k);
            acc0 = mfma16(a, b0, acc0); acc1 = mfma16(a, b1, acc1);
        }
    }
    #pragma unroll
    for (int ni = 0; ni < 2; ++ni) {
        f32x4 acc = ni == 0 ? acc0 : acc1;
        int n = npair * 32 + ni * 16 + lrow;
        float bias = sb0[b * HH + n];
        if (mf < 4) {
            #pragma unroll
            for (int r = 0; r < 4; ++r) {
                int t = mf * 16 + quad * 4 + r;
                float pre = acc[r] + bias;
                float sig = 1.f / (1.f + expf(-pre));
                size_t idx = (size_t)(b * TT + t) * HH + n;
                h1_bf[idx] = f2bf(pre * sig);
                dsil[idx]  = sig * (1.f + pre * (1.f - sig));
            }
        } else if (quad == 0) {
            float pre = acc[0] + bias;
            float sig = 1.f / (1.f + expf(-pre));
            hret[b * HH + n] = pre * sig;
        }
    }
}

// ---------------- K3: [h1;hret] @ sW1^T -> dp/pred (sW1 read once, L3-warm) ----------------
__global__ void __launch_bounds__(256) k_p(
        const unsigned short* __restrict__ h1_bf, const float* __restrict__ hret,
        const float* __restrict__ vb,
        const float* __restrict__ sW1, const float* __restrict__ sb1,
        unsigned short* __restrict__ dp_bf, float* __restrict__ pred) {
    const int blk = blockIdx.x, j = threadIdx.x;
    const int b = blk / 15;
    const int wid = j >> 6, L = j & 63;
    const int w = (blk % 15) * 4 + wid;
    const int mf = w % 5, npair = w / 5;
    const int lrow = L & 15, kq = (L >> 4) * 8, quad = L >> 4;
    const unsigned short* Abf = h1_bf + (size_t)(b * TT + mf * 16 + lrow) * HH;
    const float* Aq = hret + (size_t)b * HH;
    const int n0 = npair * 32 + lrow;
    const float* B0 = sW1 + (size_t)(b * CC + n0) * HH;
    const float* B1 = B0 + 16 * HH;
    f32x4 acc0 = {0,0,0,0}, acc1 = {0,0,0,0};
    if (mf < 4) {
        #pragma unroll 2
        for (int s = 0; s < HH / 32; ++s) {
            int k = s * 32 + kq;
            bf16x8 a = ldbf8(Abf + k);
            bf16x8 b0 = ldcvt8(B0 + k), b1 = ldcvt8(B1 + k);
            acc0 = mfma16(a, b0, acc0); acc1 = mfma16(a, b1, acc1);
        }
    } else {
        #pragma unroll 2
        for (int s = 0; s < HH / 32; ++s) {
            int k = s * 32 + kq;
            bf16x8 a = ldcvt8(Aq + k);
            bf16x8 b0 = ldcvt8(B0 + k), b1 = ldcvt8(B1 + k);
            acc0 = mfma16(a, b0, acc0); acc1 = mfma16(a, b1, acc1);
        }
    }
    #pragma unroll
    for (int ni = 0; ni < 2; ++ni) {
        f32x4 acc = ni == 0 ? acc0 : acc1;
        int n = npair * 32 + ni * 16 + lrow;
        float bias = sb1[b * CC + n];
        if (mf < 4) {
            #pragma unroll
            for (int r = 0; r < 4; ++r) {
                int t = mf * 16 + quad * 4 + r;
                size_t idx = (size_t)(b * TT + t) * CC + n;
                dp_bf[idx] = f2bf(acc[r] + bias - vb[idx]);
            }
        } else if (quad == 0) {
            pred[b * CC + n] = acc[0] + bias;
        }
    }
}

// ---------------- K4: epilogue ----------------
// blocks [0,288):   nW1 32c x 64h tiles (+nb1 on h0==0)
// blocks [288,576): nW0 32h x 64c tiles, dh1p recomputed inline via MFMA with
//                   LDS-staged bf16 sW1 column-slice (+nb0 on c0==0)
// blocks [576,624): out = pred @ Wo^T + bo
__global__ void __launch_bounds__(256) k_epi(
        const unsigned short* __restrict__ dp_bf,
        const unsigned short* __restrict__ h1_bf,
        const unsigned short* __restrict__ kb_bf,
        const float* __restrict__ dsil,
        const float* __restrict__ sW0, const float* __restrict__ sb0,
        const float* __restrict__ sW1, const float* __restrict__ sb1,
        const float* __restrict__ pred,
        const float* __restrict__ Wo, const float* __restrict__ bo,
        float* __restrict__ out, Coefs cf) {
    // unioned LDS: nW0 branch needs 384*33 bf16 (25344 B) + a_t 8192 B + e_t 16384 B = 49920 B
    __shared__ __align__(16) unsigned char sbuf[49920];
    const int blk = blockIdx.x, j = threadIdx.x;
    if (blk < 288) {                      // nW1 tile
        float* a_t = (float*)sbuf;                 // [64][32]
        float* e_t = (float*)(sbuf + 8192);        // [64][64]
        const int b = blk / 144, rem = blk % 144;
        const int c0 = (rem / 12) * 32, h0 = (rem % 12) * 64;
        for (int i = j; i < TT * 32; i += 256) {
            int t = i >> 5, c = i & 31;
            a_t[t * 32 + c] = cf.ct[t] * bf2f(dp_bf[((size_t)(b * TT + t)) * CC + c0 + c]);
        }
        for (int i = j; i < TT * 64; i += 256) {
            int t = i >> 6, h = i & 63;
            e_t[t * 64 + h] = bf2f(h1_bf[((size_t)(b * TT + t)) * HH + h0 + h]);
        }
        __syncthreads();
        const int ci = j & 31, hb = (j >> 5) * 8;
        float acc[8] = {0, 0, 0, 0, 0, 0, 0, 0};
        for (int t = 0; t < TT; ++t) {
            float av = a_t[t * 32 + ci];
            #pragma unroll
            for (int m = 0; m < 8; ++m) acc[m] += av * e_t[t * 64 + hb + m];
        }
        const size_t idx = ((size_t)b * CC + c0 + ci) * HH + h0 + hb;
        const float4* w4 = (const float4*)(sW1 + idx);
        float4 wa = w4[0], wb = w4[1];
        float4 o0, o1;
        o0.x = cf.dfac * wa.x - acc[0]; o0.y = cf.dfac * wa.y - acc[1];
        o0.z = cf.dfac * wa.z - acc[2]; o0.w = cf.dfac * wa.w - acc[3];
        o1.x = cf.dfac * wb.x - acc[4]; o1.y = cf.dfac * wb.y - acc[5];
        o1.z = cf.dfac * wb.z - acc[6]; o1.w = cf.dfac * wb.w - acc[7];
        *(float4*)(out + O_NW1 + idx) = o0;
        *(float4*)(out + O_NW1 + idx + 4) = o1;
        if (h0 == 0 && j < 32) {
            float s = 0.f;
            for (int t = 0; t < TT; ++t) s += a_t[t * 32 + j];
            out[O_NB1 + b * CC + c0 + j] = cf.dfac * sb1[b * CC + c0 + j] - s;
        }
    } else if (blk < 576) {               // nW0 tile with inline dh1p (LDS-staged sW1 slice)
        unsigned short* ldsT = (unsigned short*)sbuf;        // [384][33] bf16: [c][hl]
        float* a_t = (float*)(sbuf + 25344);                 // [64][32]
        float* e_t = (float*)(sbuf + 25344 + 8192);          // [64][64]
        const int u = blk - 288;
        const int b = u / 144, rem = u % 144;
        const int h0 = (rem / 6) * 32, c0 = (rem % 6) * 64;
        // stage sW1[b, 0:384, h0:h0+32] -> ldsT[c][hl] (coalesced 128B rows; banks (c+hl)%32-free)
        {
            const int hl = j & 31, cs = j >> 5;               // 8 c-rows per pass
            const float* base = sW1 + (size_t)b * CC * HH + h0 + hl;
            for (int c = cs; c < CC; c += 8)
                ldsT[c * 33 + hl] = f2bf(base[(size_t)c * HH]);
        }
        // e_t = kb slice
        for (int i = j; i < TT * 64; i += 256) {
            int t = i >> 6, c = i & 63;
            e_t[t * 64 + c] = bf2f(kb_bf[((size_t)(b * TT + t)) * CC + c0 + c]);
        }
        __syncthreads();
        // dh1 = dp @ sW1[:, h0:h0+32] via MFMA, B-fragments from LDS
        const int wid = j >> 6, L = j & 63;
        const int lrow = L & 15, kq = (L >> 4) * 8, quad = L >> 4;
        const unsigned short* Abf = dp_bf + (size_t)(b * TT + wid * 16 + lrow) * CC;
        f32x4 acc0 = {0,0,0,0}, acc1 = {0,0,0,0};
        for (int s = 0; s < CC / 32; ++s) {
            int k = s * 32 + kq;
            bf16x8 a = ldbf8(Abf + k);
            bf16x8 b0, b1;
            #pragma unroll
            for (int i = 0; i < 8; ++i) {
                b0[i] = (short)ldsT[(k + i) * 33 + lrow];
                b1[i] = (short)ldsT[(k + i) * 33 + 16 + lrow];
            }
            acc0 = mfma16(a, b0, acc0); acc1 = mfma16(a, b1, acc1);
        }
        #pragma unroll
        for (int ni = 0; ni < 2; ++ni) {
            f32x4 acc = ni == 0 ? acc0 : acc1;
            int hl = ni * 16 + lrow;
            #pragma unroll
            for (int r = 0; r < 4; ++r) {
                int t = wid * 16 + quad * 4 + r;
                float ds = dsil[(size_t)(b * TT + t) * HH + h0 + hl];
                a_t[t * 32 + hl] = cf.ct[t] * (acc[r] * ds);
            }
        }
        __syncthreads();
        const int hi = j & 31, cb = (j >> 5) * 8;
        float acc[8] = {0, 0, 0, 0, 0, 0, 0, 0};
        for (int t = 0; t < TT; ++t) {
            float av = a_t[t * 32 + hi];
            #pragma unroll
            for (int m = 0; m < 8; ++m) acc[m] += av * e_t[t * 64 + cb + m];
        }
        const size_t idx = ((size_t)b * HH + h0 + hi) * CC + c0 + cb;
        const float4* w4 = (const float4*)(sW0 + idx);
        float4 wa = w4[0], wb = w4[1];
        float4 o0, o1;
        o0.x = cf.dfac * wa.x - acc[0]; o0.y = cf.dfac * wa.y - acc[1];
        o0.z = cf.dfac * wa.z - acc[2]; o0.w = cf.dfac * wa.w - acc[3];
        o1.x = cf.dfac * wb.x - acc[4]; o1.y = cf.dfac * wb.y - acc[5];
        o1.z = cf.dfac * wb.z - acc[6]; o1.w = cf.dfac * wb.w - acc[7];
        *(float4*)(out + O_NW0 + idx) = o0;
        *(float4*)(out + O_NW0 + idx + 4) = o1;
        if (c0 == 0 && j < 32) {
            float s = 0.f;
            for (int t = 0; t < TT; ++t) s += a_t[t * 32 + j];
            out[O_NB0 + b * HH + h0 + j] = cf.dfac * sb0[b * HH + h0 + j] - s;
        }
    } else {                              // out = pred@Wo^T + bo
        float* vecs = (float*)sbuf;
        float* part = (float*)(sbuf + 4096);
        const int rb = blk - 576;
        const int b = rb / 24, nt = rb % 24;
        if (j < CC / 4) ((float4*)vecs)[j] = ((const float4*)(pred + b * CC))[j];
        __syncthreads();
        const int nl = j & 15, ks = j >> 4;
        const int n = nt * 16 + nl;
        const float4* wr = (const float4*)(Wo + (size_t)n * CC + ks * 24);
        float s = 0.f;
        #pragma unroll
        for (int i = 0; i < 6; ++i) {
            float4 a = wr[i];
            const float* v = vecs + ks * 24 + i * 4;
            s += a.x * v[0] + a.y * v[1] + a.z * v[2] + a.w * v[3];
        }
        part[ks * 17 + nl] = s;
        __syncthreads();
        if (j < 16) {
            int n2 = nt * 16 + j;
            float acc = bo[n2];
            #pragma unroll
            for (int kk = 0; kk < 16; ++kk) acc += part[kk * 17 + j];
            out[O_OUT + b * CC + n2] = acc;
        }
    }
}

extern "C" void kernel_launch(void* const* d_in, const int* in_sizes, int n_in,
                              void* d_out, int out_size, void* d_ws, size_t ws_size,
                              hipStream_t stream) {
    const float* x   = (const float*)d_in[0];
    const float* Wq  = (const float*)d_in[1];
    const float* bq  = (const float*)d_in[2];
    const float* Wk  = (const float*)d_in[3];
    const float* bk  = (const float*)d_in[4];
    const float* Wv  = (const float*)d_in[5];
    const float* bv  = (const float*)d_in[6];
    const float* Wo  = (const float*)d_in[7];
    const float* bo  = (const float*)d_in[8];
    const float* iq  = (const float*)d_in[9];
    const float* sW0 = (const float*)d_in[10];
    const float* sb0 = (const float*)d_in[11];
    const float* sW1 = (const float*)d_in[12];
    const float* sb1 = (const float*)d_in[13];

    float* fw = (float*)d_ws;
    float* qb   = fw;                 // 384
    float* hret = qb + 384;           // 1536
    float* pred = hret + 1536;        // 768
    float* vb   = pred + 768;         // 49152
    float* dsil = vb + 49152;         // 98304
    float* warm = dsil + 98304;       // 4 (sink, never written in practice)
    unsigned short* us = (unsigned short*)(warm + 4);
    unsigned short* kb_bf = us;              // 49152
    unsigned short* h1_bf = kb_bf + 49152;   // 98304
    unsigned short* dp_bf = h1_bf + 98304;   // 49152

    // Closed-form scan coefficients (exact: the clipped seed gate cancels).
    Coefs cf;
    const double mom = 0.9, decay = 1.0 - 0.001, lr = 0.01;
    for (int s = 0; s < TT; ++s) {
        double sum = 0.0;
        for (int t = s; t < TT; ++t) sum += pow(decay, (double)(TT - 1 - t)) * pow(mom, (double)(t - s));
        cf.ct[s] = (float)(lr * (1.0 - mom) * sum);
    }
    cf.dfac = (float)pow(decay, (double)TT);

    k_qkv<<<dim3(563), dim3(256), 0, stream>>>(x, Wk, bk, Wv, bv, Wq, bq, iq, sW0, sW1, Wo,
                                               kb_bf, vb, qb, warm);
    k_h1 <<<dim3(60),  dim3(256), 0, stream>>>(kb_bf, qb, sW0, sb0, h1_bf, dsil, hret);
    k_p  <<<dim3(30),  dim3(256), 0, stream>>>(h1_bf, hret, vb, sW1, sb1, dp_bf, pred);
    k_epi<<<dim3(624), dim3(256), 0, stream>>>(dp_bf, h1_bf, kb_bf, dsil, sW0, sb0, sW1, sb1,
                                               pred, Wo, bo, (float*)d_out, cf);
}